// Round 7
// baseline (284.933 us; speedup 1.0000x reference)
//
#include <hip/hip_runtime.h>
#include <hip/hip_bf16.h>

#define N_NODES 50000
#define N_EDGES 800000
#define D 128
#define LABEL_DIM 32
#define REL_DIM 32
#define REL_BUCKETS 1024
#define NUM_LABELS 1000
#define LN_EPS 1e-5f

#define CAPN 64      // per-node CSR capacity (max observed deg ~40 for Poisson(16))
#define EPB 1024     // edges per bin block (4/thread)
#define NE_BLOCKS 782
#define GEMM_BLOCKS 782

#define PB_IN 80      // 128*160/256
#define PB_LEMB 125   // 32000/256
#define PB_CAT 144    // 128*288/256 per layer
#define PB_REL 32     // 32768/1024 per layer
#define PB_ZERO 49    // 50000 ints / (256*4)
#define PREP_GRID (PB_IN + PB_LEMB + 2 * PB_CAT + 2 * PB_REL + PB_ZERO)  // 606

#define BSTR 144     // bounce LDS row stride in shorts

typedef short bf16x8 __attribute__((ext_vector_type(8)));
typedef float f32x4 __attribute__((ext_vector_type(4)));
typedef float f32x2 __attribute__((ext_vector_type(2)));
typedef unsigned int u32x2 __attribute__((ext_vector_type(2)));
typedef unsigned int u32x4 __attribute__((ext_vector_type(4)));

__device__ inline unsigned short f2bf(float f) {
    __hip_bfloat16 h = __float2bfloat16(f);
    return *reinterpret_cast<unsigned short*>(&h);
}
__device__ inline float bf2f(unsigned short u) {
    return __uint_as_float((unsigned)u << 16);
}

__device__ inline void pack8_fp8(const bf16x8 bv, unsigned& lo, unsigned& hi) {
    float f0 = bf2f((unsigned short)bv[0]), f1 = bf2f((unsigned short)bv[1]);
    float f2 = bf2f((unsigned short)bv[2]), f3 = bf2f((unsigned short)bv[3]);
    float f4 = bf2f((unsigned short)bv[4]), f5 = bf2f((unsigned short)bv[5]);
    float f6 = bf2f((unsigned short)bv[6]), f7 = bf2f((unsigned short)bv[7]);
    lo = __builtin_amdgcn_cvt_pk_fp8_f32(f0, f1, 0u, false);
    lo = __builtin_amdgcn_cvt_pk_fp8_f32(f2, f3, lo, true);
    hi = __builtin_amdgcn_cvt_pk_fp8_f32(f4, f5, 0u, false);
    hi = __builtin_amdgcn_cvt_pk_fp8_f32(f6, f7, hi, true);
}

// ---------------- K0: weight/embedding prep + dcnt zeroing ----------------
__global__ __launch_bounds__(256) void prep_zero_kernel(
    const float* __restrict__ in_proj_w, const float* __restrict__ label_emb,
    const float* __restrict__ lin_neigh_w, const float* __restrict__ lin_self_w,
    const float* __restrict__ lin_rel_w, const float* __restrict__ rel_emb,
    unsigned short* __restrict__ Btx, unsigned short* __restrict__ leb,
    unsigned short* __restrict__ Btc0, unsigned short* __restrict__ Btc1,
    unsigned short* __restrict__ relb0, unsigned short* __restrict__ relb1,
    int* __restrict__ dcnt) {
    int u = blockIdx.x;
    const int t = threadIdx.x;
    if (u < PB_IN) {
        int idx = u * 256 + t;
        int n = idx / 160, k = idx % 160;
        Btx[idx] = f2bf(in_proj_w[k * 128 + n]);
        return;
    }
    u -= PB_IN;
    if (u < PB_LEMB) {
        int i = u * 256 + t;
        if (i < NUM_LABELS * LABEL_DIM) leb[i] = f2bf(label_emb[i]);
        return;
    }
    u -= PB_LEMB;
    if (u < 2 * PB_CAT) {
        int l = u >= PB_CAT;
        int cb = l ? u - PB_CAT : u;
        int idx = cb * 256 + t;           // 0..36863
        int n = idx / 288, k = idx % 288; // Btc[n*288 + k] = Wcat[k][n]
        const float* Ws = lin_self_w + (size_t)l * 128 * 128;
        const float* Wn = lin_neigh_w + (size_t)l * 128 * 128;
        const float* Wr = lin_rel_w + (size_t)l * REL_DIM * 128;
        float v = (k < 128) ? Ws[(size_t)k * 128 + n]
                : (k < 256) ? Wn[(size_t)(k - 128) * 128 + n]
                            : Wr[(size_t)(k - 256) * 128 + n];
        (l ? Btc1 : Btc0)[idx] = f2bf(v);
        return;
    }
    u -= 2 * PB_CAT;
    if (u < 2 * PB_REL) {   // rel_emb fp32 -> bf16 tables
        int l = u >= PB_REL;
        int rb = l ? u - PB_REL : u;
        int idx = rb * 1024 + t * 4;
        float4 v = *(const float4*)(rel_emb + (size_t)l * REL_BUCKETS * REL_DIM + idx);
        unsigned short* out = (l ? relb1 : relb0) + idx;
        out[0] = f2bf(v.x); out[1] = f2bf(v.y);
        out[2] = f2bf(v.z); out[3] = f2bf(v.w);
        return;
    }
    u -= 2 * PB_REL;
    {   // zero dcnt (12500 int4s)
        int idx4 = u * 256 + t;
        if (idx4 < N_NODES / 4) ((int4*)dcnt)[idx4] = make_int4(0, 0, 0, 0);
    }
}

// ---------------- K1: edge bin (0..781) || input-proj GEMM (782..1563) ----------------
__global__ __launch_bounds__(256) void bin_in_kernel(
    const int* __restrict__ src, const int* __restrict__ dst, const int* __restrict__ rel,
    int* __restrict__ dcnt, unsigned* __restrict__ csr_pk,
    const float* __restrict__ X, const unsigned short* __restrict__ Btx,
    const unsigned short* __restrict__ leb, const int* __restrict__ label,
    const float* __restrict__ bias, unsigned short* __restrict__ hb,
    unsigned char* __restrict__ hb8) {
    __shared__ __align__(16) char smem[128 * 160 * 2];   // 40 KiB
    const int t = threadIdx.x;
    const int bid = blockIdx.x;

    if (bid < NE_BLOCKS) {
        // single-pass CSR: direct placement into per-node fixed-capacity rows
        const int e0 = bid * EPB;
#pragma unroll
        for (int i = 0; i < 4; ++i) {
            int e = e0 + i * 256 + t;
            if (e < N_EDGES) {
                int d = dst[e];
                int slot = atomicAdd(&dcnt[d], 1);
                if (slot < CAPN)
                    csr_pk[(size_t)d * CAPN + slot] =
                        (unsigned)src[e] | ((unsigned)rel[e] << 16);
            }
        }
        return;
    }

    // ---- input-proj MFMA GEMM (fp32 A, K=160, fused label-emb + bias + relu) ----
    unsigned short* sB = (unsigned short*)smem;
    const int mb = bid - NE_BLOCKS;   // 0..781
#pragma unroll
    for (int i = 0; i < 10; ++i) {
        int c = t + i * 256;
        int col = c / 20, kch = c % 20;
        int dstc = col * 20 + (kch < 16 ? (kch ^ (col & 7)) : kch);
        *(bf16x8*)&sB[dstc * 8] = *(const bf16x8*)&Btx[c * 8];
    }
    __syncthreads();

    const int wave = t >> 6, lane = t & 63;
    const int m16 = lane & 15, q = lane >> 4;
    const int r0 = mb * 64 + wave * 16;
    const int arow = r0 + m16;
    const bool avalid = arow < N_NODES;
    const float* xp = X + (size_t)(avalid ? arow : 0) * 128 + q * 8;

    f32x4 acc[8];
#pragma unroll
    for (int ct = 0; ct < 8; ++ct) acc[ct] = (f32x4){0.f, 0.f, 0.f, 0.f};

#pragma unroll
    for (int ki = 0; ki < 4; ++ki) {
        bf16x8 af;
        if (avalid) {
            float4 v0 = *(const float4*)(xp + ki * 32);
            float4 v1 = *(const float4*)(xp + ki * 32 + 4);
            af[0] = (short)f2bf(v0.x); af[1] = (short)f2bf(v0.y);
            af[2] = (short)f2bf(v0.z); af[3] = (short)f2bf(v0.w);
            af[4] = (short)f2bf(v1.x); af[5] = (short)f2bf(v1.y);
            af[6] = (short)f2bf(v1.z); af[7] = (short)f2bf(v1.w);
        } else {
            af = (bf16x8){0, 0, 0, 0, 0, 0, 0, 0};
        }
        int kch = ki * 4 + q;
#pragma unroll
        for (int ct = 0; ct < 8; ++ct) {
            int col = ct * 16 + m16;
            int chunk = col * 20 + (kch ^ (m16 & 7));
            bf16x8 bf = *(const bf16x8*)&sB[chunk * 8];
            acc[ct] = __builtin_amdgcn_mfma_f32_16x16x32_bf16(af, bf, acc[ct], 0, 0, 0);
        }
    }
    {
        int lb = avalid ? label[arow] : 0;
        bf16x8 af = *(const bf16x8*)(leb + (size_t)lb * LABEL_DIM + q * 8);
        if (!avalid) af = (bf16x8){0, 0, 0, 0, 0, 0, 0, 0};
        int kch = 16 + q;
#pragma unroll
        for (int ct = 0; ct < 8; ++ct) {
            int col = ct * 16 + m16;
            int chunk = col * 20 + kch;
            bf16x8 bf = *(const bf16x8*)&sB[chunk * 8];
            acc[ct] = __builtin_amdgcn_mfma_f32_16x16x32_bf16(af, bf, acc[ct], 0, 0, 0);
        }
    }

    unsigned short hbv[8][4];
#pragma unroll
    for (int ct = 0; ct < 8; ++ct) {
        int colg = ct * 16 + m16;
        float bs = bias[colg];
#pragma unroll
        for (int r = 0; r < 4; ++r) {
            int row = r0 + q * 4 + r;
            float v = fmaxf(acc[ct][r] + bs, 0.f);
            hbv[ct][r] = f2bf(v);
            if (row < N_NODES) hb[(size_t)row * 128 + colg] = hbv[ct][r];
        }
    }

    // fp8 shadow copy via LDS bounce
    __syncthreads();
    unsigned short* bounce = sB;
#pragma unroll
    for (int ct = 0; ct < 8; ++ct) {
        int colg = ct * 16 + m16;
#pragma unroll
        for (int r = 0; r < 4; ++r)
            bounce[(wave * 16 + q * 4 + r) * BSTR + colg] = hbv[ct][r];
    }
    __syncthreads();
    {
        int rl = t >> 2;
        int grow = mb * 64 + rl;
        if (grow < N_NODES) {
            const unsigned short* bp = bounce + rl * BSTR + (t & 3) * 32;
            unsigned o[8];
#pragma unroll
            for (int k = 0; k < 4; ++k) {
                bf16x8 bv = *(const bf16x8*)(bp + k * 8);
                pack8_fp8(bv, o[2 * k], o[2 * k + 1]);
            }
            u32x4* dp = (u32x4*)(hb8 + (size_t)grow * 128 + (t & 3) * 32);
            dp[0] = (u32x4){o[0], o[1], o[2], o[3]};
            dp[1] = (u32x4){o[4], o[5], o[6], o[7]};
        }
    }
}

// ---------------- K2/K3: fused layer = agg (own 64 rows) + K=288 GEMM + LN ----------------
// Block owns rows r0..r0+63. Each wave aggregates its 16 rows into LDS (Sm/Rm never
// touch global), then split-B-staged GEMM accumulates self+neigh+rel, LN epilogue.
// hb8 ping-pongs across layers (in != out) to avoid cross-block read/write races.
template <bool LAST>
__global__ __launch_bounds__(256) void layer_kernel(
    const unsigned short* __restrict__ Btc,
    unsigned short* __restrict__ hb,          // self input (own rows) + output (!LAST)
    const unsigned char* __restrict__ hb8_in, // gather input
    unsigned char* __restrict__ hb8_out,      // fp8 output (!LAST)
    const unsigned short* __restrict__ relb,
    const int* __restrict__ dcnt, const unsigned* __restrict__ csr_pk,
    const float* __restrict__ bias, const float* __restrict__ g,
    const float* __restrict__ b, float* __restrict__ hout) {
    __shared__ __align__(16) unsigned short sB[128 * 20 * 8];   // 40 KiB (staged twice)
    __shared__ __align__(16) unsigned short sm_s[64 * 128];     // 16 KiB swizzled Sm
    __shared__ __align__(16) unsigned rm_s[64 * 16];            // 4 KiB swizzled Rm

    const int t = threadIdx.x;
    const int wave = t >> 6, lane = t & 63;
    const int m16 = lane & 15, q = lane >> 4;
    const int r0 = blockIdx.x * 64;
    const int arow = r0 + wave * 16 + m16;
    const bool avalid = arow < N_NODES;
    const int sr = avalid ? arow : 0;

    // preload self A fragments (prefetches under agg latency)
    bf16x8 aself[4];
    {
        const unsigned short* hp = hb + (size_t)sr * 128 + q * 8;
        const bf16x8 zf = (bf16x8){0, 0, 0, 0, 0, 0, 0, 0};
#pragma unroll
        for (int ki = 0; ki < 4; ++ki) {
            bf16x8 af = *(const bf16x8*)(hp + ki * 32);
            aself[ki] = avalid ? af : zf;
        }
    }

    // stage B1: self K-chunks 0..15 (32 KiB)
#pragma unroll
    for (int i = 0; i < 8; ++i) {
        int c = t + i * 256;              // < 2048
        int col = c >> 4, kc = c & 15;
        *(bf16x8*)&sB[(col * 16 + (kc ^ (col & 7))) * 8] = *(const bf16x8*)&Btc[(col * 36 + kc) * 8];
    }
    __syncthreads();

    // ---- agg phase: wave aggregates its 16 nodes into sm_s/rm_s ----
    {
        const int node_base = r0 + wave * 16;
        const int l16 = m16;
        const int co = l16 * 8;
        int dcv = 0;
        {
            int nb = node_base + lane;
            if (lane < 16 && nb < N_NODES) dcv = dcnt[nb];
        }
        int dc_next = __shfl(dcv, 0);
        dc_next = dc_next < CAPN ? dc_next : CAPN;
        unsigned pk_cur = 0;
        if (lane < dc_next) pk_cur = csr_pk[(size_t)node_base * CAPN + lane];

        for (int i = 0; i < 16; ++i) {
            const int dc = dc_next;
            const int dtrue = __shfl(dcv, i);
            unsigned pk_next = 0;
            if (i < 15) {
                dc_next = __shfl(dcv, i + 1);
                dc_next = dc_next < CAPN ? dc_next : CAPN;
                if (lane < dc_next) pk_next = csr_pk[(size_t)(node_base + i + 1) * CAPN + lane];
            }
            float acc[8];
#pragma unroll
            for (int j = 0; j < 8; ++j) acc[j] = 0.f;
            float ra0 = 0.f, ra1 = 0.f;

            for (int s = 0; s < dc; s += 16) {
                unsigned pkk[4];
                float mk[4];
#pragma unroll
                for (int k = 0; k < 4; ++k) {
                    int slot = s + k * 4 + q;       // <= 63
                    pkk[k] = (unsigned)__shfl((int)pk_cur, slot);
                    mk[k] = (slot < dc) ? 1.f : 0.f;
                }
#pragma unroll
                for (int k = 0; k < 4; ++k) {
                    u32x2 hv = *(const u32x2*)(hb8_in + ((size_t)(pkk[k] & 0xffffu) << 7) + co);
                    unsigned rw = *(const unsigned*)(relb + ((size_t)(pkk[k] >> 16) << 5) + l16 * 2);
                    float m = mk[k];
                    f32x2 d0 = __builtin_amdgcn_cvt_pk_f32_fp8(hv[0], false);
                    f32x2 d1 = __builtin_amdgcn_cvt_pk_f32_fp8(hv[0], true);
                    f32x2 d2 = __builtin_amdgcn_cvt_pk_f32_fp8(hv[1], false);
                    f32x2 d3 = __builtin_amdgcn_cvt_pk_f32_fp8(hv[1], true);
                    acc[0] = fmaf(m, d0[0], acc[0]); acc[1] = fmaf(m, d0[1], acc[1]);
                    acc[2] = fmaf(m, d1[0], acc[2]); acc[3] = fmaf(m, d1[1], acc[3]);
                    acc[4] = fmaf(m, d2[0], acc[4]); acc[5] = fmaf(m, d2[1], acc[5]);
                    acc[6] = fmaf(m, d3[0], acc[6]); acc[7] = fmaf(m, d3[1], acc[7]);
                    ra0 = fmaf(m, bf2f((unsigned short)(rw & 0xffffu)), ra0);
                    ra1 = fmaf(m, bf2f((unsigned short)(rw >> 16)), ra1);
                }
            }
#pragma unroll
            for (int j = 0; j < 8; ++j) {
                acc[j] += __shfl_xor(acc[j], 16);
                acc[j] += __shfl_xor(acc[j], 32);
            }
            ra0 += __shfl_xor(ra0, 16); ra0 += __shfl_xor(ra0, 32);
            ra1 += __shfl_xor(ra1, 16); ra1 += __shfl_xor(ra1, 32);

            if (q == 0) {
                float inv = (dtrue > 0) ? 1.f / (float)dtrue : 0.f;
                bf16x8 ob;
#pragma unroll
                for (int j = 0; j < 8; ++j) ob[j] = (short)f2bf(acc[j] * inv);
                int row = wave * 16 + i;
                *(bf16x8*)&sm_s[(row * 16 + (l16 ^ (row & 7))) * 8] = ob;
                rm_s[row * 16 + (l16 ^ ((row & 3) << 2))] =
                    (unsigned)f2bf(ra0 * inv) | ((unsigned)f2bf(ra1 * inv) << 16);
            }
            pk_cur = pk_next;
        }
    }

    // ---- GEMM: self part (B1) ----
    f32x4 acc[8];
#pragma unroll
    for (int ct = 0; ct < 8; ++ct) acc[ct] = (f32x4){0.f, 0.f, 0.f, 0.f};
#pragma unroll
    for (int ki = 0; ki < 4; ++ki) {
        int kch = ki * 4 + q;
#pragma unroll
        for (int ct = 0; ct < 8; ++ct) {
            int col = ct * 16 + m16;
            bf16x8 bf = *(const bf16x8*)&sB[(col * 16 + (kch ^ (m16 & 7))) * 8];
            acc[ct] = __builtin_amdgcn_mfma_f32_16x16x32_bf16(aself[ki], bf, acc[ct], 0, 0, 0);
        }
    }
    __syncthreads();

    // stage B2: neigh K-chunks 16..31 + rel 32..35 remapped to 0..19 (40 KiB)
#pragma unroll
    for (int i = 0; i < 10; ++i) {
        int c = t + i * 256;              // < 2560
        int col = c / 20, j = c % 20;
        int swz = (j < 16) ? (j ^ (col & 7)) : (16 + ((j - 16) ^ (col & 3)));
        *(bf16x8*)&sB[(col * 20 + swz) * 8] = *(const bf16x8*)&Btc[(col * 36 + 16 + j) * 8];
    }
    __syncthreads();

    // ---- GEMM: neigh-mean (Sm from LDS) + rel-mean (Rm from LDS) ----
    // A-row for this lane is LOCAL row lr = wave*16 + m16 (R6 bug: was m16 alone).
    const int lr = wave * 16 + m16;
#pragma unroll
    for (int ki = 0; ki < 4; ++ki) {
        int kch = ki * 4 + q;
        bf16x8 af = *(const bf16x8*)&sm_s[(lr * 16 + (kch ^ (m16 & 7))) * 8];
#pragma unroll
        for (int ct = 0; ct < 8; ++ct) {
            int col = ct * 16 + m16;
            bf16x8 bf = *(const bf16x8*)&sB[(col * 20 + (kch ^ (m16 & 7))) * 8];
            acc[ct] = __builtin_amdgcn_mfma_f32_16x16x32_bf16(af, bf, acc[ct], 0, 0, 0);
        }
    }
    {
        bf16x8 af = *(const bf16x8*)&rm_s[lr * 16 + ((q * 4) ^ ((m16 & 3) << 2))];
#pragma unroll
        for (int ct = 0; ct < 8; ++ct) {
            int col = ct * 16 + m16;
            bf16x8 bf = *(const bf16x8*)&sB[(col * 20 + 16 + (q ^ (m16 & 3))) * 8];
            acc[ct] = __builtin_amdgcn_mfma_f32_16x16x32_bf16(af, bf, acc[ct], 0, 0, 0);
        }
    }

    // ---- epilogue: bias + relu + layernorm per row ----
    float bs[8], gs[8], bbs[8];
#pragma unroll
    for (int ct = 0; ct < 8; ++ct) {
        int cg2 = ct * 16 + m16;
        bs[ct] = bias[cg2];
        gs[ct] = g[cg2];
        bbs[ct] = b[cg2];
    }
    const int rw0 = r0 + wave * 16;
    unsigned short hbv[4][8];
#pragma unroll
    for (int r = 0; r < 4; ++r) {
        int row = rw0 + q * 4 + r;
        float v[8];
        float s = 0.f;
#pragma unroll
        for (int ct = 0; ct < 8; ++ct) {
            float val = fmaxf(acc[ct][r] + bs[ct], 0.f);
            v[ct] = val;
            s += val;
        }
#pragma unroll
        for (int o = 8; o > 0; o >>= 1) s += __shfl_xor(s, o);
        float mu = s * (1.f / 128.f);
        float qs = 0.f;
#pragma unroll
        for (int ct = 0; ct < 8; ++ct) {
            float dd = v[ct] - mu;
            v[ct] = dd;
            qs += dd * dd;
        }
#pragma unroll
        for (int o = 8; o > 0; o >>= 1) qs += __shfl_xor(qs, o);
        float rstd = rsqrtf(qs * (1.f / 128.f) + LN_EPS);
#pragma unroll
        for (int ct = 0; ct < 8; ++ct) {
            int colg = ct * 16 + m16;
            float o2 = v[ct] * rstd * gs[ct] + bbs[ct];
            hbv[r][ct] = f2bf(o2);
            if (row < N_NODES) {
                if constexpr (LAST) {
                    hout[(size_t)row * 128 + colg] = o2;
                } else {
                    hb[(size_t)row * 128 + colg] = hbv[r][ct];
                }
            }
        }
    }

    if constexpr (!LAST) {
        // fp8 shadow copy via LDS bounce (reuse sB)
        __syncthreads();
        unsigned short* bounce = sB;
#pragma unroll
        for (int r = 0; r < 4; ++r) {
            int rl = wave * 16 + q * 4 + r;
#pragma unroll
            for (int ct = 0; ct < 8; ++ct)
                bounce[rl * BSTR + ct * 16 + m16] = hbv[r][ct];
        }
        __syncthreads();
        int rl = t >> 2;
        int grow = r0 + rl;
        if (grow < N_NODES) {
            const unsigned short* bp = bounce + rl * BSTR + (t & 3) * 32;
            unsigned o[8];
#pragma unroll
            for (int k = 0; k < 4; ++k) {
                bf16x8 bv = *(const bf16x8*)(bp + k * 8);
                pack8_fp8(bv, o[2 * k], o[2 * k + 1]);
            }
            u32x4* dp = (u32x4*)(hb8_out + (size_t)grow * 128 + (t & 3) * 32);
            dp[0] = (u32x4){o[0], o[1], o[2], o[3]};
            dp[1] = (u32x4){o[4], o[5], o[6], o[7]};
        }
    }
}

// ---------------- launch ----------------

extern "C" void kernel_launch(void* const* d_in, const int* in_sizes, int n_in,
                              void* d_out, int out_size, void* d_ws, size_t ws_size,
                              hipStream_t stream) {
    const float* x          = (const float*)d_in[0];
    const int*   label      = (const int*)d_in[1];
    const int*   edge_index = (const int*)d_in[2];
    const int*   edge_rel   = (const int*)d_in[3];
    const float* label_emb  = (const float*)d_in[4];
    const float* in_proj_w  = (const float*)d_in[5];
    const float* in_proj_b  = (const float*)d_in[6];
    const float* rel_emb    = (const float*)d_in[7];
    const float* lin_neigh_w = (const float*)d_in[8];
    const float* lin_self_w  = (const float*)d_in[9];
    const float* lin_self_b  = (const float*)d_in[10];
    const float* lin_rel_w   = (const float*)d_in[11];
    const float* ln_g        = (const float*)d_in[12];
    const float* ln_b        = (const float*)d_in[13];
    float* h = (float*)d_out;

    char* p = (char*)d_ws;
    auto alloc = [&](size_t bytes) {
        char* r = p;
        p += (bytes + 255) & ~(size_t)255;
        return r;
    };
    int* dcnt        = (int*)alloc((size_t)N_NODES * 4);
    unsigned* csr_pk = (unsigned*)alloc((size_t)N_NODES * CAPN * 4);
    unsigned short* hb   = (unsigned short*)alloc((size_t)N_NODES * 128 * 2);
    unsigned char*  hb8a = (unsigned char*)alloc((size_t)N_NODES * 128);
    unsigned char*  hb8b = (unsigned char*)alloc((size_t)N_NODES * 128);
    unsigned short* Btx  = (unsigned short*)alloc((size_t)128 * 160 * 2);
    unsigned short* leb  = (unsigned short*)alloc((size_t)NUM_LABELS * LABEL_DIM * 2);
    unsigned short* Btc0 = (unsigned short*)alloc((size_t)128 * 288 * 2);
    unsigned short* Btc1 = (unsigned short*)alloc((size_t)128 * 288 * 2);
    unsigned short* relb0 = (unsigned short*)alloc((size_t)REL_BUCKETS * REL_DIM * 2);
    unsigned short* relb1 = (unsigned short*)alloc((size_t)REL_BUCKETS * REL_DIM * 2);

    const int* src = edge_index;
    const int* dst = edge_index + N_EDGES;

    // K0: prep + zero dcnt
    prep_zero_kernel<<<PREP_GRID, 256, 0, stream>>>(
        in_proj_w, label_emb, lin_neigh_w, lin_self_w, lin_rel_w, rel_emb,
        Btx, leb, Btc0, Btc1, relb0, relb1, dcnt);

    // K1: edge bin || input-proj GEMM
    bin_in_kernel<<<NE_BLOCKS + GEMM_BLOCKS, 256, 0, stream>>>(
        src, dst, edge_rel, dcnt, csr_pk,
        x, Btx, leb, label, in_proj_b, hb, hb8a);

    // K2: layer 0 (reads hb8a, writes hb + hb8b)
    layer_kernel<false><<<GEMM_BLOCKS, 256, 0, stream>>>(
        Btc0, hb, hb8a, hb8b, relb0, dcnt, csr_pk,
        lin_self_b, ln_g, ln_b, nullptr);

    // K3: layer 1 (reads hb8b, writes hout)
    layer_kernel<true><<<GEMM_BLOCKS, 256, 0, stream>>>(
        Btc1, hb, hb8b, nullptr, relb1, dcnt, csr_pk,
        lin_self_b + 128, ln_g + 128, ln_b + 128, h);
}

// Round 8
// 267.295 us; speedup vs baseline: 1.0660x; 1.0660x over previous
//
#include <hip/hip_runtime.h>
#include <hip/hip_bf16.h>

#define N_NODES 50000
#define N_EDGES 800000
#define D 128
#define LABEL_DIM 32
#define REL_DIM 32
#define REL_BUCKETS 1024
#define NUM_LABELS 1000
#define LN_EPS 1e-5f

#define NB 196       // dst buckets of 256 nodes (for LDS sort)
#define CAPN 64      // per-node CSR capacity (deg ~ Poisson(16); P(>64) ~ 1e-19; validated R7)
#define EPB 1024     // edges per edge block (4/thread)
#define NE_BLOCKS 782
#define GEMM_BLOCKS 782

#define PB_CAT 144    // 128*288/256 per layer
#define PB_REL 32     // 32768/1024 per layer
#define PREP2 (2 * PB_CAT + 2 * PB_REL)   // 352
#define COMBO_GRID (NE_BLOCKS + GEMM_BLOCKS + PREP2)  // 1916

#define BSTR 144     // bounce LDS row stride in shorts

typedef short bf16x8 __attribute__((ext_vector_type(8)));
typedef float f32x4 __attribute__((ext_vector_type(4)));
typedef float f32x2 __attribute__((ext_vector_type(2)));
typedef unsigned int u32x2 __attribute__((ext_vector_type(2)));
typedef unsigned int u32x4 __attribute__((ext_vector_type(4)));

__device__ inline unsigned short f2bf(float f) {
    __hip_bfloat16 h = __float2bfloat16(f);
    return *reinterpret_cast<unsigned short*>(&h);
}
__device__ inline float bf2f(unsigned short u) {
    return __uint_as_float((unsigned)u << 16);
}

__device__ inline void pack8_fp8(const bf16x8 bv, unsigned& lo, unsigned& hi) {
    float f0 = bf2f((unsigned short)bv[0]), f1 = bf2f((unsigned short)bv[1]);
    float f2 = bf2f((unsigned short)bv[2]), f3 = bf2f((unsigned short)bv[3]);
    float f4 = bf2f((unsigned short)bv[4]), f5 = bf2f((unsigned short)bv[5]);
    float f6 = bf2f((unsigned short)bv[6]), f7 = bf2f((unsigned short)bv[7]);
    lo = __builtin_amdgcn_cvt_pk_fp8_f32(f0, f1, 0u, false);
    lo = __builtin_amdgcn_cvt_pk_fp8_f32(f2, f3, lo, true);
    hi = __builtin_amdgcn_cvt_pk_fp8_f32(f4, f5, 0u, false);
    hi = __builtin_amdgcn_cvt_pk_fp8_f32(f6, f7, hi, true);
}

// ---------------- K1 combo: edge-sort CSR (0..781) || input GEMM (782..1563) || prep (1564..) ----
__global__ __launch_bounds__(256) void combo_kernel(
    const int* __restrict__ src, const int* __restrict__ dst, const int* __restrict__ rel,
    int* __restrict__ dcnt, unsigned* __restrict__ csr_pk,
    const float* __restrict__ X, const int* __restrict__ label,
    const float* __restrict__ in_proj_w, const float* __restrict__ label_emb,
    const float* __restrict__ in_proj_b,
    const float* __restrict__ lin_neigh_w, const float* __restrict__ lin_self_w,
    const float* __restrict__ lin_rel_w, const float* __restrict__ rel_emb,
    unsigned short* __restrict__ Btc0, unsigned short* __restrict__ Btc1,
    unsigned short* __restrict__ relb0, unsigned short* __restrict__ relb1,
    unsigned short* __restrict__ hb, unsigned char* __restrict__ hb8) {
    __shared__ __align__(16) char smem[128 * 160 * 2];   // 40 KiB union
    const int t = threadIdx.x;
    const int bid = blockIdx.x;

    if (bid < NE_BLOCKS) {
        // ---- LDS bucket-sort + direct per-node placement ----
        int* hist = (int*)smem;                       // 196
        int* cur = hist + NB;                         // 196
        int* buf = cur + NB;                          // 256
        unsigned* spk = (unsigned*)(buf + 256);       // 1024
        unsigned short* sd = (unsigned short*)(spk + EPB);  // 1024

        for (int i = t; i < NB; i += 256) hist[i] = 0;
        __syncthreads();
        const int e0 = bid * EPB;
        const int cnt = min(EPB, N_EDGES - e0);
        int ed[4];
        unsigned epk[4];
        bool ok[4];
#pragma unroll
        for (int i = 0; i < 4; ++i) {
            int e = e0 + i * 256 + t;
            ok[i] = e < N_EDGES;
            if (ok[i]) {
                int d = dst[e];
                ed[i] = d;
                epk[i] = (unsigned)src[e] | ((unsigned)rel[e] << 16);
                atomicAdd(&hist[d >> 8], 1);
            }
        }
        __syncthreads();
        int v = (t < NB) ? hist[t] : 0;
        buf[t] = v;
        __syncthreads();
        for (int o = 1; o < 256; o <<= 1) {
            int tv = (t >= o) ? buf[t - o] : 0;
            __syncthreads();
            buf[t] += tv;
            __syncthreads();
        }
        if (t < NB) cur[t] = buf[t] - v;
        __syncthreads();
#pragma unroll
        for (int i = 0; i < 4; ++i) {
            if (ok[i]) {
                int pos = atomicAdd(&cur[ed[i] >> 8], 1);
                spk[pos] = epk[i];
                sd[pos] = (unsigned short)ed[i];
            }
        }
        __syncthreads();
        // placement: consecutive threads handle same-bucket edges -> dcnt atomics and
        // csr writes localized to a 64 KB window
#pragma unroll
        for (int i = 0; i < 4; ++i) {
            int idx = t + i * 256;
            if (idx < cnt) {
                int d = sd[idx];
                int slot = atomicAdd(&dcnt[d], 1);
                if (slot < CAPN) csr_pk[(size_t)d * CAPN + slot] = spk[idx];
            }
        }
        return;
    }

    if (bid >= NE_BLOCKS + GEMM_BLOCKS) {
        // ---- weight prep: Btc (K=288 concat, transposed+bf16) and relb tables ----
        int u = bid - NE_BLOCKS - GEMM_BLOCKS;
        if (u < 2 * PB_CAT) {
            int l = u >= PB_CAT;
            int cb = l ? u - PB_CAT : u;
            int idx = cb * 256 + t;           // 0..36863
            int n = idx / 288, k = idx % 288; // Btc[n*288 + k] = Wcat[k][n]
            const float* Ws = lin_self_w + (size_t)l * 128 * 128;
            const float* Wn = lin_neigh_w + (size_t)l * 128 * 128;
            const float* Wr = lin_rel_w + (size_t)l * REL_DIM * 128;
            float v = (k < 128) ? Ws[(size_t)k * 128 + n]
                    : (k < 256) ? Wn[(size_t)(k - 128) * 128 + n]
                                : Wr[(size_t)(k - 256) * 128 + n];
            (l ? Btc1 : Btc0)[idx] = f2bf(v);
            return;
        }
        u -= 2 * PB_CAT;
        {   // rel_emb fp32 -> bf16 tables
            int l = u >= PB_REL;
            int rb = l ? u - PB_REL : u;
            int idx = rb * 1024 + t * 4;
            float4 v = *(const float4*)(rel_emb + (size_t)l * REL_BUCKETS * REL_DIM + idx);
            unsigned short* out = (l ? relb1 : relb0) + idx;
            out[0] = f2bf(v.x); out[1] = f2bf(v.y);
            out[2] = f2bf(v.z); out[3] = f2bf(v.w);
            return;
        }
    }

    // ---- input-proj MFMA GEMM (fp32 A, K=160) staging B DIRECTLY from fp32 weights ----
    unsigned short* sB = (unsigned short*)smem;
    const int mb = bid - NE_BLOCKS;   // 0..781
#pragma unroll
    for (int i = 0; i < 10; ++i) {
        int c = t + i * 256;          // chunk < 2560
        int col = c / 20, kch = c % 20;
        int swz = (kch < 16) ? (kch ^ (col & 7)) : kch;
        bf16x8 bv;
#pragma unroll
        for (int j = 0; j < 8; ++j)
            bv[j] = (short)f2bf(in_proj_w[(size_t)(kch * 8 + j) * 128 + col]);
        *(bf16x8*)&sB[(col * 20 + swz) * 8] = bv;
    }
    __syncthreads();

    const int wave = t >> 6, lane = t & 63;
    const int m16 = lane & 15, q = lane >> 4;
    const int r0 = mb * 64 + wave * 16;
    const int arow = r0 + m16;
    const bool avalid = arow < N_NODES;
    const float* xp = X + (size_t)(avalid ? arow : 0) * 128 + q * 8;

    f32x4 acc[8];
#pragma unroll
    for (int ct = 0; ct < 8; ++ct) acc[ct] = (f32x4){0.f, 0.f, 0.f, 0.f};

#pragma unroll
    for (int ki = 0; ki < 4; ++ki) {
        bf16x8 af;
        if (avalid) {
            float4 v0 = *(const float4*)(xp + ki * 32);
            float4 v1 = *(const float4*)(xp + ki * 32 + 4);
            af[0] = (short)f2bf(v0.x); af[1] = (short)f2bf(v0.y);
            af[2] = (short)f2bf(v0.z); af[3] = (short)f2bf(v0.w);
            af[4] = (short)f2bf(v1.x); af[5] = (short)f2bf(v1.y);
            af[6] = (short)f2bf(v1.z); af[7] = (short)f2bf(v1.w);
        } else {
            af = (bf16x8){0, 0, 0, 0, 0, 0, 0, 0};
        }
        int kch = ki * 4 + q;
#pragma unroll
        for (int ct = 0; ct < 8; ++ct) {
            int col = ct * 16 + m16;
            int chunk = col * 20 + (kch ^ (m16 & 7));
            bf16x8 bf = *(const bf16x8*)&sB[chunk * 8];
            acc[ct] = __builtin_amdgcn_mfma_f32_16x16x32_bf16(af, bf, acc[ct], 0, 0, 0);
        }
    }
    {
        int lb = avalid ? label[arow] : 0;
        const float* lp = label_emb + (size_t)lb * LABEL_DIM + q * 8;
        float4 v0 = *(const float4*)lp;
        float4 v1 = *(const float4*)(lp + 4);
        bf16x8 af;
        af[0] = (short)f2bf(v0.x); af[1] = (short)f2bf(v0.y);
        af[2] = (short)f2bf(v0.z); af[3] = (short)f2bf(v0.w);
        af[4] = (short)f2bf(v1.x); af[5] = (short)f2bf(v1.y);
        af[6] = (short)f2bf(v1.z); af[7] = (short)f2bf(v1.w);
        if (!avalid) af = (bf16x8){0, 0, 0, 0, 0, 0, 0, 0};
        int kch = 16 + q;
#pragma unroll
        for (int ct = 0; ct < 8; ++ct) {
            int col = ct * 16 + m16;
            int chunk = col * 20 + kch;
            bf16x8 bf = *(const bf16x8*)&sB[chunk * 8];
            acc[ct] = __builtin_amdgcn_mfma_f32_16x16x32_bf16(af, bf, acc[ct], 0, 0, 0);
        }
    }

    unsigned short hbv[8][4];
#pragma unroll
    for (int ct = 0; ct < 8; ++ct) {
        int colg = ct * 16 + m16;
        float bs = in_proj_b[colg];
#pragma unroll
        for (int r = 0; r < 4; ++r) {
            int row = r0 + q * 4 + r;
            float v = fmaxf(acc[ct][r] + bs, 0.f);
            hbv[ct][r] = f2bf(v);
            if (row < N_NODES) hb[(size_t)row * 128 + colg] = hbv[ct][r];
        }
    }

    // fp8 shadow copy via LDS bounce
    __syncthreads();
    unsigned short* bounce = sB;
#pragma unroll
    for (int ct = 0; ct < 8; ++ct) {
        int colg = ct * 16 + m16;
#pragma unroll
        for (int r = 0; r < 4; ++r)
            bounce[(wave * 16 + q * 4 + r) * BSTR + colg] = hbv[ct][r];
    }
    __syncthreads();
    {
        int rl = t >> 2;
        int grow = mb * 64 + rl;
        if (grow < N_NODES) {
            const unsigned short* bp = bounce + rl * BSTR + (t & 3) * 32;
            unsigned o[8];
#pragma unroll
            for (int k = 0; k < 4; ++k) {
                bf16x8 bv = *(const bf16x8*)(bp + k * 8);
                pack8_fp8(bv, o[2 * k], o[2 * k + 1]);
            }
            u32x4* dp = (u32x4*)(hb8 + (size_t)grow * 128 + (t & 3) * 32);
            dp[0] = (u32x4){o[0], o[1], o[2], o[3]};
            dp[1] = (u32x4){o[4], o[5], o[6], o[7]};
        }
    }
}

// ---------------- raw-neighbor aggregation (fp8 h rows + bf16 rel rows) ----------------
// One wave per node; coalesced pk prefetch (node*CAPN layout) + 16 edges in flight.
__global__ __launch_bounds__(256) void agg_raw_kernel(const unsigned char* __restrict__ hb8,
                                                      const unsigned short* __restrict__ relb,
                                                      const int* __restrict__ dcnt,
                                                      const unsigned* __restrict__ csr_pk,
                                                      unsigned short* __restrict__ Sm,
                                                      unsigned short* __restrict__ Rm) {
    const int wave = threadIdx.x >> 6;
    const int lane = threadIdx.x & 63;
    const int node = blockIdx.x * 4 + wave;
    if (node >= N_NODES) return;
    const int q = lane >> 4, l16 = lane & 15;
    const int dtrue = dcnt[node];
    const int dc = dtrue < CAPN ? dtrue : CAPN;
    const int co = l16 * 8;

    float acc[8];
    float ra0 = 0.f, ra1 = 0.f;
#pragma unroll
    for (int j = 0; j < 8; ++j) acc[j] = 0.f;

    unsigned pkv = 0;
    if (lane < dc) pkv = csr_pk[(size_t)node * CAPN + lane];

    for (int s = 0; s < dc; s += 16) {
        unsigned pkk[4];
        float mk[4];
#pragma unroll
        for (int k = 0; k < 4; ++k) {
            int slot = s + k * 4 + q;          // <= 63
            pkk[k] = (unsigned)__shfl((int)pkv, slot);
            mk[k] = (slot < dc) ? 1.f : 0.f;   // masked lanes read row 0 (safe)
        }
#pragma unroll
        for (int k = 0; k < 4; ++k) {
            u32x2 hv = *(const u32x2*)(hb8 + ((size_t)(pkk[k] & 0xffffu) << 7) + co);
            unsigned rw = *(const unsigned*)(relb + ((size_t)(pkk[k] >> 16) << 5) + l16 * 2);
            float m = mk[k];
            f32x2 d0 = __builtin_amdgcn_cvt_pk_f32_fp8(hv[0], false);
            f32x2 d1 = __builtin_amdgcn_cvt_pk_f32_fp8(hv[0], true);
            f32x2 d2 = __builtin_amdgcn_cvt_pk_f32_fp8(hv[1], false);
            f32x2 d3 = __builtin_amdgcn_cvt_pk_f32_fp8(hv[1], true);
            acc[0] = fmaf(m, d0[0], acc[0]); acc[1] = fmaf(m, d0[1], acc[1]);
            acc[2] = fmaf(m, d1[0], acc[2]); acc[3] = fmaf(m, d1[1], acc[3]);
            acc[4] = fmaf(m, d2[0], acc[4]); acc[5] = fmaf(m, d2[1], acc[5]);
            acc[6] = fmaf(m, d3[0], acc[6]); acc[7] = fmaf(m, d3[1], acc[7]);
            ra0 = fmaf(m, bf2f((unsigned short)(rw & 0xffffu)), ra0);
            ra1 = fmaf(m, bf2f((unsigned short)(rw >> 16)), ra1);
        }
    }

#pragma unroll
    for (int j = 0; j < 8; ++j) {
        acc[j] += __shfl_xor(acc[j], 16);
        acc[j] += __shfl_xor(acc[j], 32);
    }
    ra0 += __shfl_xor(ra0, 16); ra0 += __shfl_xor(ra0, 32);
    ra1 += __shfl_xor(ra1, 16); ra1 += __shfl_xor(ra1, 32);

    float inv = (dtrue > 0) ? 1.f / (float)dtrue : 0.f;
    if (q == 0) {
        bf16x8 ob;
#pragma unroll
        for (int j = 0; j < 8; ++j) ob[j] = (short)f2bf(acc[j] * inv);
        *(bf16x8*)(Sm + ((size_t)node << 7) + co) = ob;
        unsigned pk = (unsigned)f2bf(ra0 * inv) | ((unsigned)f2bf(ra1 * inv) << 16);
        ((unsigned*)(Rm + ((size_t)node << 5)))[l16] = pk;
    }
}

// ---------------- fused K=288 GEMM [h|Sm|Rm]@[Wself;Wneigh;Wrel] + bias+relu+LN ----
template <bool LAST>
__global__ __launch_bounds__(256) void gemm_ln_kernel(const unsigned short* __restrict__ Btc,
                                                      unsigned short* __restrict__ hb,
                                                      unsigned char* __restrict__ hb8,
                                                      const unsigned short* __restrict__ Sm,
                                                      const unsigned short* __restrict__ Rm,
                                                      const float* __restrict__ bias,
                                                      const float* __restrict__ g,
                                                      const float* __restrict__ b,
                                                      float* __restrict__ hout) {
    __shared__ unsigned short sB[128 * 36 * 8];  // 72 KiB
    const int t = threadIdx.x;
#pragma unroll
    for (int i = 0; i < 18; ++i) {
        int c = t + i * 256;  // chunk id < 4608
        int col = c / 36, kch = c % 36;
        int swz = (kch < 32) ? (kch ^ (col & 7)) : (32 + ((kch - 32) ^ (col & 3)));
        *(bf16x8*)&sB[(col * 36 + swz) * 8] = *(const bf16x8*)&Btc[c * 8];
    }
    __syncthreads();

    const int wave = t >> 6, lane = t & 63;
    const int m16 = lane & 15, q = lane >> 4;
    const int r0 = blockIdx.x * 64 + wave * 16;
    const int arow = r0 + m16;
    const bool avalid = arow < N_NODES;
    const int sr = avalid ? arow : 0;
    const unsigned short* hp = hb + (size_t)sr * 128 + q * 8;
    const unsigned short* sp = Sm + (size_t)sr * 128 + q * 8;
    const unsigned short* rp = Rm + (size_t)sr * 32 + q * 8;

    f32x4 acc[8];
#pragma unroll
    for (int ct = 0; ct < 8; ++ct) acc[ct] = (f32x4){0.f, 0.f, 0.f, 0.f};
    const bf16x8 zf = (bf16x8){0, 0, 0, 0, 0, 0, 0, 0};

#pragma unroll
    for (int ki = 0; ki < 4; ++ki) {  // k 0..127: self
        bf16x8 af = *(const bf16x8*)(hp + ki * 32);
        if (!avalid) af = zf;
        int kch = ki * 4 + q;
#pragma unroll
        for (int ct = 0; ct < 8; ++ct) {
            int col = ct * 16 + m16;
            bf16x8 bf = *(const bf16x8*)&sB[(col * 36 + (kch ^ (m16 & 7))) * 8];
            acc[ct] = __builtin_amdgcn_mfma_f32_16x16x32_bf16(af, bf, acc[ct], 0, 0, 0);
        }
    }
#pragma unroll
    for (int ki = 0; ki < 4; ++ki) {  // k 128..255: neigh-mean
        bf16x8 af = *(const bf16x8*)(sp + ki * 32);
        if (!avalid) af = zf;
        int kch = 16 + ki * 4 + q;
#pragma unroll
        for (int ct = 0; ct < 8; ++ct) {
            int col = ct * 16 + m16;
            bf16x8 bf = *(const bf16x8*)&sB[(col * 36 + (kch ^ (m16 & 7))) * 8];
            acc[ct] = __builtin_amdgcn_mfma_f32_16x16x32_bf16(af, bf, acc[ct], 0, 0, 0);
        }
    }
    {  // k 256..287: rel-mean
        bf16x8 af = *(const bf16x8*)rp;
        if (!avalid) af = zf;
#pragma unroll
        for (int ct = 0; ct < 8; ++ct) {
            int col = ct * 16 + m16;
            bf16x8 bf = *(const bf16x8*)&sB[(col * 36 + 32 + (q ^ (m16 & 3))) * 8];
            acc[ct] = __builtin_amdgcn_mfma_f32_16x16x32_bf16(af, bf, acc[ct], 0, 0, 0);
        }
    }

    // epilogue: bias + relu + layernorm per row (16 lanes of same q hold one row)
    float bs[8], gs[8], bbs[8];
#pragma unroll
    for (int ct = 0; ct < 8; ++ct) {
        int cg2 = ct * 16 + m16;
        bs[ct] = bias[cg2];
        gs[ct] = g[cg2];
        bbs[ct] = b[cg2];
    }
    unsigned short hbv[4][8];
#pragma unroll
    for (int r = 0; r < 4; ++r) {
        int row = r0 + q * 4 + r;
        float v[8];
        float s = 0.f;
#pragma unroll
        for (int ct = 0; ct < 8; ++ct) {
            float val = fmaxf(acc[ct][r] + bs[ct], 0.f);
            v[ct] = val;
            s += val;
        }
#pragma unroll
        for (int o = 8; o > 0; o >>= 1) s += __shfl_xor(s, o);
        float mu = s * (1.f / 128.f);
        float qs = 0.f;
#pragma unroll
        for (int ct = 0; ct < 8; ++ct) {
            float dd = v[ct] - mu;
            v[ct] = dd;
            qs += dd * dd;
        }
#pragma unroll
        for (int o = 8; o > 0; o >>= 1) qs += __shfl_xor(qs, o);
        float rstd = rsqrtf(qs * (1.f / 128.f) + LN_EPS);
#pragma unroll
        for (int ct = 0; ct < 8; ++ct) {
            int colg = ct * 16 + m16;
            float o2 = v[ct] * rstd * gs[ct] + bbs[ct];
            hbv[r][ct] = f2bf(o2);
            if (row < N_NODES) {
                if constexpr (LAST) {
                    hout[(size_t)row * 128 + colg] = o2;
                } else {
                    hb[(size_t)row * 128 + colg] = hbv[r][ct];
                }
            }
        }
    }

    if constexpr (!LAST) {
        // fp8 shadow copy via LDS bounce
        __syncthreads();
        unsigned short* bounce = sB;
#pragma unroll
        for (int r = 0; r < 4; ++r) {
            int rl = wave * 16 + q * 4 + r;
#pragma unroll
            for (int ct = 0; ct < 8; ++ct)
                bounce[rl * BSTR + ct * 16 + m16] = hbv[r][ct];
        }
        __syncthreads();
        int rl = t >> 2;
        int grow = blockIdx.x * 64 + rl;
        if (grow < N_NODES) {
            const unsigned short* bp = bounce + rl * BSTR + (t & 3) * 32;
            unsigned o[8];
#pragma unroll
            for (int k = 0; k < 4; ++k) {
                bf16x8 bv = *(const bf16x8*)(bp + k * 8);
                pack8_fp8(bv, o[2 * k], o[2 * k + 1]);
            }
            u32x4* dp = (u32x4*)(hb8 + (size_t)grow * 128 + (t & 3) * 32);
            dp[0] = (u32x4){o[0], o[1], o[2], o[3]};
            dp[1] = (u32x4){o[4], o[5], o[6], o[7]};
        }
    }
}

// ---------------- launch ----------------

extern "C" void kernel_launch(void* const* d_in, const int* in_sizes, int n_in,
                              void* d_out, int out_size, void* d_ws, size_t ws_size,
                              hipStream_t stream) {
    const float* x          = (const float*)d_in[0];
    const int*   label      = (const int*)d_in[1];
    const int*   edge_index = (const int*)d_in[2];
    const int*   edge_rel   = (const int*)d_in[3];
    const float* label_emb  = (const float*)d_in[4];
    const float* in_proj_w  = (const float*)d_in[5];
    const float* in_proj_b  = (const float*)d_in[6];
    const float* rel_emb    = (const float*)d_in[7];
    const float* lin_neigh_w = (const float*)d_in[8];
    const float* lin_self_w  = (const float*)d_in[9];
    const float* lin_self_b  = (const float*)d_in[10];
    const float* lin_rel_w   = (const float*)d_in[11];
    const float* ln_g        = (const float*)d_in[12];
    const float* ln_b        = (const float*)d_in[13];
    float* h = (float*)d_out;

    char* p = (char*)d_ws;
    auto alloc = [&](size_t bytes) {
        char* r = p;
        p += (bytes + 255) & ~(size_t)255;
        return r;
    };
    int* dcnt        = (int*)alloc((size_t)N_NODES * 4);
    unsigned* csr_pk = (unsigned*)alloc((size_t)N_NODES * CAPN * 4);
    unsigned short* hb  = (unsigned short*)alloc((size_t)N_NODES * 128 * 2);
    unsigned char*  hb8 = (unsigned char*)alloc((size_t)N_NODES * 128);
    unsigned short* Sm  = (unsigned short*)alloc((size_t)N_NODES * 128 * 2);
    unsigned short* Rm  = (unsigned short*)alloc((size_t)N_NODES * 32 * 2);
    unsigned short* Btc0 = (unsigned short*)alloc((size_t)128 * 288 * 2);
    unsigned short* Btc1 = (unsigned short*)alloc((size_t)128 * 288 * 2);
    unsigned short* relb0 = (unsigned short*)alloc((size_t)REL_BUCKETS * REL_DIM * 2);
    unsigned short* relb1 = (unsigned short*)alloc((size_t)REL_BUCKETS * REL_DIM * 2);

    const int* src = edge_index;
    const int* dst = edge_index + N_EDGES;

    // 0) zero per-node counters
    hipMemsetAsync(dcnt, 0, (size_t)N_NODES * 4, stream);

    // 1) edge-sort CSR || input-proj GEMM || weight prep (one dispatch)
    combo_kernel<<<COMBO_GRID, 256, 0, stream>>>(
        src, dst, edge_rel, dcnt, csr_pk,
        x, label, in_proj_w, label_emb, in_proj_b,
        lin_neigh_w, lin_self_w, lin_rel_w, rel_emb,
        Btc0, Btc1, relb0, relb1, hb, hb8);

    const int gemm_grid = (N_NODES + 63) / 64;  // 782
    const int agg_grid = (N_NODES + 3) / 4;     // 12500

    // 2-3) layer 0
    agg_raw_kernel<<<agg_grid, 256, 0, stream>>>(
        hb8, relb0, dcnt, csr_pk, Sm, Rm);
    gemm_ln_kernel<false><<<gemm_grid, 256, 0, stream>>>(
        Btc0, hb, hb8, Sm, Rm, lin_self_b, ln_g, ln_b, nullptr);
    // 4-5) layer 1
    agg_raw_kernel<<<agg_grid, 256, 0, stream>>>(
        hb8, relb1, dcnt, csr_pk, Sm, Rm);
    gemm_ln_kernel<true><<<gemm_grid, 256, 0, stream>>>(
        Btc1, hb, hb8, Sm, Rm, lin_self_b + 128, ln_g + 128, ln_b + 128, h);
}

// Round 9
// 226.140 us; speedup vs baseline: 1.2600x; 1.1820x over previous
//
#include <hip/hip_runtime.h>
#include <hip/hip_bf16.h>

#define N_NODES 50000
#define N_EDGES 800000
#define D 128
#define LABEL_DIM 32
#define REL_DIM 32
#define REL_BUCKETS 1024
#define NUM_LABELS 1000
#define LN_EPS 1e-5f

#define NB 196       // dst buckets of 256 nodes
#define CAP 6144     // fixed per-bucket capacity (mean load 4082, +32 sigma headroom)
#define EPB 1024     // edges per scatter block (4/thread)
#define NE_BLOCKS 782

#define PB_IN 80      // 128*160/256
#define PB_LEMB 125   // 32000/256
#define PB_CAT 144    // 128*288/256 per layer
#define PB_REL 32     // 32768/1024 per layer
#define PREP_UNITS (PB_IN + PB_LEMB + 2 * PB_CAT + 2 * PB_REL)   // 557

#define BSTR 144     // bounce LDS row stride in shorts (288B, 16B-aligned rows)

typedef short bf16x8 __attribute__((ext_vector_type(8)));
typedef float f32x4 __attribute__((ext_vector_type(4)));
typedef float f32x2 __attribute__((ext_vector_type(2)));
typedef unsigned int u32x2 __attribute__((ext_vector_type(2)));
typedef unsigned int u32x4 __attribute__((ext_vector_type(4)));

__device__ inline unsigned short f2bf(float f) {
    __hip_bfloat16 h = __float2bfloat16(f);
    return *reinterpret_cast<unsigned short*>(&h);
}
__device__ inline float bf2f(unsigned short u) {
    return __uint_as_float((unsigned)u << 16);
}

// pack 8 bf16 (as shorts) -> 8 fp8 e4m3 bytes (2 dwords) via HW cvt
__device__ inline void pack8_fp8(const bf16x8 bv, unsigned& lo, unsigned& hi) {
    float f0 = bf2f((unsigned short)bv[0]), f1 = bf2f((unsigned short)bv[1]);
    float f2 = bf2f((unsigned short)bv[2]), f3 = bf2f((unsigned short)bv[3]);
    float f4 = bf2f((unsigned short)bv[4]), f5 = bf2f((unsigned short)bv[5]);
    float f6 = bf2f((unsigned short)bv[6]), f7 = bf2f((unsigned short)bv[7]);
    lo = __builtin_amdgcn_cvt_pk_fp8_f32(f0, f1, 0u, false);
    lo = __builtin_amdgcn_cvt_pk_fp8_f32(f2, f3, lo, true);
    hi = __builtin_amdgcn_cvt_pk_fp8_f32(f4, f5, 0u, false);
    hi = __builtin_amdgcn_cvt_pk_fp8_f32(f6, f7, hi, true);
}

// ---------------- fused: edge scatter (blocks 0..781) || weight prep (782..) ----------------
__global__ __launch_bounds__(256) void scatter_prep_kernel(
    const int* __restrict__ src, const int* __restrict__ dst, const int* __restrict__ rel,
    int* __restrict__ gcur, unsigned* __restrict__ staged_pk, unsigned char* __restrict__ staged_dl,
    const float* __restrict__ in_proj_w, const float* __restrict__ label_emb,
    const float* __restrict__ lin_neigh_w, const float* __restrict__ lin_self_w,
    const float* __restrict__ lin_rel_w, const float* __restrict__ rel_emb,
    unsigned short* __restrict__ Btx, unsigned short* __restrict__ leb,
    unsigned short* __restrict__ Btc0, unsigned short* __restrict__ Btc1,
    unsigned short* __restrict__ relb0, unsigned short* __restrict__ relb1) {
    __shared__ int hist[NB];
    __shared__ int lcur[NB];
    const int t = threadIdx.x;
    const int bid = blockIdx.x;

    if (bid >= NE_BLOCKS) {
        int u = bid - NE_BLOCKS;
        if (u < PB_IN) {
            int idx = u * 256 + t;
            int n = idx / 160, k = idx % 160;
            Btx[idx] = f2bf(in_proj_w[k * 128 + n]);
            return;
        }
        u -= PB_IN;
        if (u < PB_LEMB) {
            int i = u * 256 + t;
            if (i < NUM_LABELS * LABEL_DIM) leb[i] = f2bf(label_emb[i]);
            return;
        }
        u -= PB_LEMB;
        if (u < 2 * PB_CAT) {
            int l = u >= PB_CAT;
            int cb = l ? u - PB_CAT : u;
            int idx = cb * 256 + t;           // 0..36863
            int n = idx / 288, k = idx % 288; // Btc[n*288 + k] = Wcat[k][n]
            const float* Ws = lin_self_w + (size_t)l * 128 * 128;
            const float* Wn = lin_neigh_w + (size_t)l * 128 * 128;
            const float* Wr = lin_rel_w + (size_t)l * REL_DIM * 128;
            float v = (k < 128) ? Ws[(size_t)k * 128 + n]
                    : (k < 256) ? Wn[(size_t)(k - 128) * 128 + n]
                                : Wr[(size_t)(k - 256) * 128 + n];
            (l ? Btc1 : Btc0)[idx] = f2bf(v);
            return;
        }
        u -= 2 * PB_CAT;
        {   // rel_emb fp32 -> bf16 tables (halves rel gather bytes)
            int l = u >= PB_REL;
            int rb = l ? u - PB_REL : u;
            int idx = rb * 1024 + t * 4;
            float4 v = *(const float4*)(rel_emb + (size_t)l * REL_BUCKETS * REL_DIM + idx);
            unsigned short* out = (l ? relb1 : relb0) + idx;
            out[0] = f2bf(v.x); out[1] = f2bf(v.y);
            out[2] = f2bf(v.z); out[3] = f2bf(v.w);
            return;
        }
    }

    // ---- edge scatter into fixed-capacity bucket regions ----
    for (int i = t; i < NB; i += 256) hist[i] = 0;
    __syncthreads();
    const int e0 = bid * EPB;
    unsigned char bb[4], dl[4];
#pragma unroll
    for (int i = 0; i < 4; ++i) {
        int e = e0 + i * 256 + t;
        if (e < N_EDGES) {
            int d = dst[e];
            bb[i] = (unsigned char)(d >> 8);
            dl[i] = (unsigned char)(d & 255);
            atomicAdd(&hist[d >> 8], 1);
        }
    }
    __syncthreads();
    for (int b = t; b < NB; b += 256) {
        int hc = hist[b];
        lcur[b] = hc ? (b * CAP + atomicAdd(&gcur[b], hc)) : 0;
    }
    __syncthreads();
#pragma unroll
    for (int i = 0; i < 4; ++i) {
        int e = e0 + i * 256 + t;
        if (e < N_EDGES) {
            int pos = atomicAdd(&lcur[bb[i]], 1);
            staged_pk[pos] = (unsigned)src[e] | ((unsigned)rel[e] << 16);
            staged_dl[pos] = dl[i];
        }
    }
}

// ---------------- fused dispatch: per-bucket place (0..195) || input GEMM (196..977) ----------------
__global__ __launch_bounds__(256) void place_in_kernel(
    const int* __restrict__ gcur,
    const unsigned* __restrict__ staged_pk, const unsigned char* __restrict__ staged_dl,
    int* __restrict__ off, int* __restrict__ deg, unsigned* __restrict__ csr_pk,
    const float* __restrict__ X, const unsigned short* __restrict__ Btx,
    const unsigned short* __restrict__ leb, const int* __restrict__ label,
    const float* __restrict__ bias, unsigned short* __restrict__ hb,
    unsigned char* __restrict__ hb8) {
    __shared__ __align__(16) char smem[128 * 160 * 2];   // 40 KiB union
    const int t = threadIdx.x;
    const int bid = blockIdx.x;

    if (bid < NB) {
        int* ph = (int*)smem;
        int* pbuf = ph + 256;
        int* pcur = pbuf + 256;
        const int beg = bid * CAP;
        const int end = beg + gcur[bid];
        ph[t] = 0;
        __syncthreads();
        for (int i = beg + t; i < end; i += 256) atomicAdd(&ph[staged_dl[i]], 1);
        __syncthreads();
        int v = ph[t];
        pbuf[t] = v;
        __syncthreads();
        for (int o = 1; o < 256; o <<= 1) {
            int tv = (t >= o) ? pbuf[t - o] : 0;
            __syncthreads();
            pbuf[t] += tv;
            __syncthreads();
        }
        int node_off = beg + pbuf[t] - v;
        int node = bid * 256 + t;
        if (node < N_NODES) {
            off[node] = node_off;
            deg[node] = v;
        }
        pcur[t] = node_off;
        __syncthreads();
        for (int i = beg + t; i < end; i += 256) {
            int pos = atomicAdd(&pcur[staged_dl[i]], 1);
            csr_pk[pos] = staged_pk[i];
        }
        return;
    }

    // ---- input-proj MFMA GEMM (fp32 A, K=160, fused label-emb + bias + relu) ----
    unsigned short* sB = (unsigned short*)smem;
    const int mb = bid - NB;   // 0..781
#pragma unroll
    for (int i = 0; i < 10; ++i) {
        int c = t + i * 256;
        int col = c / 20, kch = c % 20;
        int dstc = col * 20 + (kch < 16 ? (kch ^ (col & 7)) : kch);
        *(bf16x8*)&sB[dstc * 8] = *(const bf16x8*)&Btx[c * 8];
    }
    __syncthreads();

    const int wave = t >> 6, lane = t & 63;
    const int m16 = lane & 15, q = lane >> 4;
    const int r0 = mb * 64 + wave * 16;
    const int arow = r0 + m16;
    const bool avalid = arow < N_NODES;
    const float* xp = X + (size_t)(avalid ? arow : 0) * 128 + q * 8;

    f32x4 acc[8];
#pragma unroll
    for (int ct = 0; ct < 8; ++ct) acc[ct] = (f32x4){0.f, 0.f, 0.f, 0.f};

#pragma unroll
    for (int ki = 0; ki < 4; ++ki) {
        bf16x8 af;
        if (avalid) {
            float4 v0 = *(const float4*)(xp + ki * 32);
            float4 v1 = *(const float4*)(xp + ki * 32 + 4);
            af[0] = (short)f2bf(v0.x); af[1] = (short)f2bf(v0.y);
            af[2] = (short)f2bf(v0.z); af[3] = (short)f2bf(v0.w);
            af[4] = (short)f2bf(v1.x); af[5] = (short)f2bf(v1.y);
            af[6] = (short)f2bf(v1.z); af[7] = (short)f2bf(v1.w);
        } else {
            af = (bf16x8){0, 0, 0, 0, 0, 0, 0, 0};
        }
        int kch = ki * 4 + q;
#pragma unroll
        for (int ct = 0; ct < 8; ++ct) {
            int col = ct * 16 + m16;
            int chunk = col * 20 + (kch ^ (m16 & 7));
            bf16x8 bf = *(const bf16x8*)&sB[chunk * 8];
            acc[ct] = __builtin_amdgcn_mfma_f32_16x16x32_bf16(af, bf, acc[ct], 0, 0, 0);
        }
    }
    {
        int lb = avalid ? label[arow] : 0;
        bf16x8 af = *(const bf16x8*)(leb + (size_t)lb * LABEL_DIM + q * 8);
        if (!avalid) af = (bf16x8){0, 0, 0, 0, 0, 0, 0, 0};
        int kch = 16 + q;
#pragma unroll
        for (int ct = 0; ct < 8; ++ct) {
            int col = ct * 16 + m16;
            int chunk = col * 20 + kch;
            bf16x8 bf = *(const bf16x8*)&sB[chunk * 8];
            acc[ct] = __builtin_amdgcn_mfma_f32_16x16x32_bf16(af, bf, acc[ct], 0, 0, 0);
        }
    }

    unsigned short hbv[8][4];
#pragma unroll
    for (int ct = 0; ct < 8; ++ct) {
        int colg = ct * 16 + m16;
        float bs = bias[colg];
#pragma unroll
        for (int r = 0; r < 4; ++r) {
            int row = r0 + q * 4 + r;
            float v = fmaxf(acc[ct][r] + bs, 0.f);
            hbv[ct][r] = f2bf(v);
            if (row < N_NODES) hb[(size_t)row * 128 + colg] = hbv[ct][r];
        }
    }

    // fp8 shadow copy via LDS bounce (accumulator cols are 16-strided; need contiguity)
    __syncthreads();
    unsigned short* bounce = sB;
#pragma unroll
    for (int ct = 0; ct < 8; ++ct) {
        int colg = ct * 16 + m16;
#pragma unroll
        for (int r = 0; r < 4; ++r)
            bounce[(wave * 16 + q * 4 + r) * BSTR + colg] = hbv[ct][r];
    }
    __syncthreads();
    {
        int rl = t >> 2;
        int grow = mb * 64 + rl;
        if (grow < N_NODES) {
            const unsigned short* bp = bounce + rl * BSTR + (t & 3) * 32;
            unsigned o[8];
#pragma unroll
            for (int k = 0; k < 4; ++k) {
                bf16x8 bv = *(const bf16x8*)(bp + k * 8);
                pack8_fp8(bv, o[2 * k], o[2 * k + 1]);
            }
            u32x4* dp = (u32x4*)(hb8 + (size_t)grow * 128 + (t & 3) * 32);
            dp[0] = (u32x4){o[0], o[1], o[2], o[3]};
            dp[1] = (u32x4){o[4], o[5], o[6], o[7]};
        }
    }
}

// ---------------- raw-neighbor aggregation (fp8 h rows + bf16 rel rows) ----------------
// Latency-optimized: coalesced csr_pk prefetch (1 load covers deg<=64) + __shfl
// distribution + 16 edges in flight per iteration (8 independent gathers/lane).
__global__ __launch_bounds__(256) void agg_raw_kernel(const unsigned char* __restrict__ hb8,
                                                      const unsigned short* __restrict__ relb,
                                                      const int* __restrict__ off,
                                                      const int* __restrict__ deg,
                                                      const unsigned* __restrict__ csr_pk,
                                                      unsigned short* __restrict__ Sm,
                                                      unsigned short* __restrict__ Rm) {
    const int wave = threadIdx.x >> 6;
    const int lane = threadIdx.x & 63;
    const int node = blockIdx.x * 4 + wave;
    if (node >= N_NODES) return;
    const int q = lane >> 4, l16 = lane & 15;
    const int beg = off[node];
    const int dcnt = deg[node];
    const int co = l16 * 8;

    float acc[8];
    float ra0 = 0.f, ra1 = 0.f;
#pragma unroll
    for (int j = 0; j < 8; ++j) acc[j] = 0.f;

    // coalesced prefetch of up to 64 packed edge records (covers ~100% of nodes)
    unsigned pkv = 0;
    if (lane < dcnt) pkv = csr_pk[beg + lane];

    const int dcl = dcnt < 64 ? dcnt : 64;
    for (int s = 0; s < dcl; s += 16) {
        unsigned pkk[4];
        float mk[4];
#pragma unroll
        for (int k = 0; k < 4; ++k) {
            int slot = s + k * 4 + q;          // <= 63 always
            pkk[k] = (unsigned)__shfl((int)pkv, slot);
            mk[k] = (slot < dcnt) ? 1.f : 0.f; // masked lanes read row 0 (safe)
        }
#pragma unroll
        for (int k = 0; k < 4; ++k) {
            u32x2 hv = *(const u32x2*)(hb8 + ((size_t)(pkk[k] & 0xffffu) << 7) + co);
            unsigned rw = *(const unsigned*)(relb + ((size_t)(pkk[k] >> 16) << 5) + l16 * 2);
            float m = mk[k];
            f32x2 d0 = __builtin_amdgcn_cvt_pk_f32_fp8(hv[0], false);
            f32x2 d1 = __builtin_amdgcn_cvt_pk_f32_fp8(hv[0], true);
            f32x2 d2 = __builtin_amdgcn_cvt_pk_f32_fp8(hv[1], false);
            f32x2 d3 = __builtin_amdgcn_cvt_pk_f32_fp8(hv[1], true);
            acc[0] = fmaf(m, d0[0], acc[0]); acc[1] = fmaf(m, d0[1], acc[1]);
            acc[2] = fmaf(m, d1[0], acc[2]); acc[3] = fmaf(m, d1[1], acc[3]);
            acc[4] = fmaf(m, d2[0], acc[4]); acc[5] = fmaf(m, d2[1], acc[5]);
            acc[6] = fmaf(m, d3[0], acc[6]); acc[7] = fmaf(m, d3[1], acc[7]);
            ra0 = fmaf(m, bf2f((unsigned short)(rw & 0xffffu)), ra0);
            ra1 = fmaf(m, bf2f((unsigned short)(rw >> 16)), ra1);
        }
    }

    // rare tail: deg > 64
    const int end = beg + dcnt;
    for (int e = beg + 64; e < end; e += 8) {
        int i0 = e + q, i1 = e + 4 + q;
        float m0 = 1.f, m1 = 1.f;
        if (i0 >= end) { i0 = beg; m0 = 0.f; }
        if (i1 >= end) { i1 = beg; m1 = 0.f; }
        unsigned pk0 = csr_pk[i0];
        unsigned pk1 = csr_pk[i1];
        u32x2 hv0 = *(const u32x2*)(hb8 + ((size_t)(pk0 & 0xffffu) << 7) + co);
        u32x2 hv1 = *(const u32x2*)(hb8 + ((size_t)(pk1 & 0xffffu) << 7) + co);
        unsigned rw0 = *(const unsigned*)(relb + ((size_t)(pk0 >> 16) << 5) + l16 * 2);
        unsigned rw1 = *(const unsigned*)(relb + ((size_t)(pk1 >> 16) << 5) + l16 * 2);
        {
            f32x2 d0 = __builtin_amdgcn_cvt_pk_f32_fp8(hv0[0], false);
            f32x2 d1 = __builtin_amdgcn_cvt_pk_f32_fp8(hv0[0], true);
            f32x2 d2 = __builtin_amdgcn_cvt_pk_f32_fp8(hv0[1], false);
            f32x2 d3 = __builtin_amdgcn_cvt_pk_f32_fp8(hv0[1], true);
            acc[0] = fmaf(m0, d0[0], acc[0]); acc[1] = fmaf(m0, d0[1], acc[1]);
            acc[2] = fmaf(m0, d1[0], acc[2]); acc[3] = fmaf(m0, d1[1], acc[3]);
            acc[4] = fmaf(m0, d2[0], acc[4]); acc[5] = fmaf(m0, d2[1], acc[5]);
            acc[6] = fmaf(m0, d3[0], acc[6]); acc[7] = fmaf(m0, d3[1], acc[7]);
        }
        {
            f32x2 d0 = __builtin_amdgcn_cvt_pk_f32_fp8(hv1[0], false);
            f32x2 d1 = __builtin_amdgcn_cvt_pk_f32_fp8(hv1[0], true);
            f32x2 d2 = __builtin_amdgcn_cvt_pk_f32_fp8(hv1[1], false);
            f32x2 d3 = __builtin_amdgcn_cvt_pk_f32_fp8(hv1[1], true);
            acc[0] = fmaf(m1, d0[0], acc[0]); acc[1] = fmaf(m1, d0[1], acc[1]);
            acc[2] = fmaf(m1, d1[0], acc[2]); acc[3] = fmaf(m1, d1[1], acc[3]);
            acc[4] = fmaf(m1, d2[0], acc[4]); acc[5] = fmaf(m1, d2[1], acc[5]);
            acc[6] = fmaf(m1, d3[0], acc[6]); acc[7] = fmaf(m1, d3[1], acc[7]);
        }
        ra0 = fmaf(m0, bf2f((unsigned short)(rw0 & 0xffffu)), ra0);
        ra1 = fmaf(m0, bf2f((unsigned short)(rw0 >> 16)), ra1);
        ra0 = fmaf(m1, bf2f((unsigned short)(rw1 & 0xffffu)), ra0);
        ra1 = fmaf(m1, bf2f((unsigned short)(rw1 >> 16)), ra1);
    }

#pragma unroll
    for (int j = 0; j < 8; ++j) {
        acc[j] += __shfl_xor(acc[j], 16);
        acc[j] += __shfl_xor(acc[j], 32);
    }
    ra0 += __shfl_xor(ra0, 16); ra0 += __shfl_xor(ra0, 32);
    ra1 += __shfl_xor(ra1, 16); ra1 += __shfl_xor(ra1, 32);

    float inv = (dcnt > 0) ? 1.f / (float)dcnt : 0.f;
    if (q == 0) {
        bf16x8 ob;
#pragma unroll
        for (int j = 0; j < 8; ++j) ob[j] = (short)f2bf(acc[j] * inv);
        *(bf16x8*)(Sm + ((size_t)node << 7) + co) = ob;
        unsigned pk = (unsigned)f2bf(ra0 * inv) | ((unsigned)f2bf(ra1 * inv) << 16);
        ((unsigned*)(Rm + ((size_t)node << 5)))[l16] = pk;
    }
}

// ---------------- fused K=288 GEMM [h|Sm|Rm]@[Wself;Wneigh;Wrel] + bias+relu+LN ----
// Split-B staging (B1 self 32KB -> MFMA -> B2 neigh+rel 40KB) keeps LDS at 40KB
// -> 4 blocks/CU (vs 2 with monolithic 72KB tile). MFMA order unchanged (identical
// numerics to the 240.4us R5 kernel); B indexing lifted from R7's refcheck'd layer GEMM.
template <bool LAST>
__global__ __launch_bounds__(256, 4) void gemm_ln_kernel(const unsigned short* __restrict__ Btc,
                                                         unsigned short* __restrict__ hb,
                                                         unsigned char* __restrict__ hb8,
                                                         const unsigned short* __restrict__ Sm,
                                                         const unsigned short* __restrict__ Rm,
                                                         const float* __restrict__ bias,
                                                         const float* __restrict__ g,
                                                         const float* __restrict__ b,
                                                         float* __restrict__ hout) {
    __shared__ unsigned short sB[128 * 20 * 8];  // 40 KiB, staged twice
    const int t = threadIdx.x;
    const int wave = t >> 6, lane = t & 63;
    const int m16 = lane & 15, q = lane >> 4;
    const int r0 = blockIdx.x * 64 + wave * 16;
    const int arow = r0 + m16;
    const bool avalid = arow < N_NODES;
    const int sr = avalid ? arow : 0;
    const unsigned short* hp = hb + (size_t)sr * 128 + q * 8;
    const unsigned short* sp = Sm + (size_t)sr * 128 + q * 8;
    const unsigned short* rp = Rm + (size_t)sr * 32 + q * 8;
    const bf16x8 zf = (bf16x8){0, 0, 0, 0, 0, 0, 0, 0};

    // preload self A fragments (independent of LDS)
    bf16x8 aself[4];
#pragma unroll
    for (int ki = 0; ki < 4; ++ki) {
        bf16x8 af = *(const bf16x8*)(hp + ki * 32);
        aself[ki] = avalid ? af : zf;
    }

    // stage B1: self K-chunks 0..15 (32 KiB)
#pragma unroll
    for (int i = 0; i < 8; ++i) {
        int c = t + i * 256;              // < 2048
        int col = c >> 4, kc = c & 15;
        *(bf16x8*)&sB[(col * 16 + (kc ^ (col & 7))) * 8] = *(const bf16x8*)&Btc[(col * 36 + kc) * 8];
    }
    __syncthreads();

    f32x4 acc[8];
#pragma unroll
    for (int ct = 0; ct < 8; ++ct) acc[ct] = (f32x4){0.f, 0.f, 0.f, 0.f};

#pragma unroll
    for (int ki = 0; ki < 4; ++ki) {  // k 0..127: self
        int kch = ki * 4 + q;
#pragma unroll
        for (int ct = 0; ct < 8; ++ct) {
            int col = ct * 16 + m16;
            bf16x8 bf = *(const bf16x8*)&sB[(col * 16 + (kch ^ (m16 & 7))) * 8];
            acc[ct] = __builtin_amdgcn_mfma_f32_16x16x32_bf16(aself[ki], bf, acc[ct], 0, 0, 0);
        }
    }
    __syncthreads();

    // stage B2: neigh K-chunks 16..31 + rel 32..35 remapped to local 0..19 (40 KiB)
#pragma unroll
    for (int i = 0; i < 10; ++i) {
        int c = t + i * 256;              // < 2560
        int col = c / 20, j = c % 20;
        int swz = (j < 16) ? (j ^ (col & 7)) : (16 + ((j - 16) ^ (col & 3)));
        *(bf16x8*)&sB[(col * 20 + swz) * 8] = *(const bf16x8*)&Btc[(col * 36 + 16 + j) * 8];
    }
    __syncthreads();

#pragma unroll
    for (int ki = 0; ki < 4; ++ki) {  // k 128..255: neigh-mean
        bf16x8 af = *(const bf16x8*)(sp + ki * 32);
        if (!avalid) af = zf;
        int kch = ki * 4 + q;         // local chunk in B2
#pragma unroll
        for (int ct = 0; ct < 8; ++ct) {
            int col = ct * 16 + m16;
            bf16x8 bf = *(const bf16x8*)&sB[(col * 20 + (kch ^ (m16 & 7))) * 8];
            acc[ct] = __builtin_amdgcn_mfma_f32_16x16x32_bf16(af, bf, acc[ct], 0, 0, 0);
        }
    }
    {  // k 256..287: rel-mean (local chunks 16..19)
        bf16x8 af = *(const bf16x8*)rp;
        if (!avalid) af = zf;
#pragma unroll
        for (int ct = 0; ct < 8; ++ct) {
            int col = ct * 16 + m16;
            bf16x8 bf = *(const bf16x8*)&sB[(col * 20 + 16 + (q ^ (m16 & 3))) * 8];
            acc[ct] = __builtin_amdgcn_mfma_f32_16x16x32_bf16(af, bf, acc[ct], 0, 0, 0);
        }
    }

    // epilogue: bias + relu + layernorm per row (16 lanes of same q hold one row)
    float bs[8], gs[8], bbs[8];
#pragma unroll
    for (int ct = 0; ct < 8; ++ct) {
        int cg2 = ct * 16 + m16;
        bs[ct] = bias[cg2];
        gs[ct] = g[cg2];
        bbs[ct] = b[cg2];
    }
    unsigned short hbv[4][8];
#pragma unroll
    for (int r = 0; r < 4; ++r) {
        int row = r0 + q * 4 + r;
        float v[8];
        float s = 0.f;
#pragma unroll
        for (int ct = 0; ct < 8; ++ct) {
            float val = fmaxf(acc[ct][r] + bs[ct], 0.f);
            v[ct] = val;
            s += val;
        }
#pragma unroll
        for (int o = 8; o > 0; o >>= 1) s += __shfl_xor(s, o);
        float mu = s * (1.f / 128.f);
        float qs = 0.f;
#pragma unroll
        for (int ct = 0; ct < 8; ++ct) {
            float dd = v[ct] - mu;
            v[ct] = dd;
            qs += dd * dd;
        }
#pragma unroll
        for (int o = 8; o > 0; o >>= 1) qs += __shfl_xor(qs, o);
        float rstd = rsqrtf(qs * (1.f / 128.f) + LN_EPS);
#pragma unroll
        for (int ct = 0; ct < 8; ++ct) {
            int colg = ct * 16 + m16;
            float o2 = v[ct] * rstd * gs[ct] + bbs[ct];
            hbv[r][ct] = f2bf(o2);
            if (row < N_NODES) {
                if constexpr (LAST) {
                    hout[(size_t)row * 128 + colg] = o2;
                } else {
                    hb[(size_t)row * 128 + colg] = hbv[r][ct];
                }
            }
        }
    }

    if constexpr (!LAST) {
        // fp8 shadow copy via LDS bounce (reuse sB: 64*BSTR = 18KB < 40KB)
        __syncthreads();
        unsigned short* bounce = sB;
#pragma unroll
        for (int r = 0; r < 4; ++r) {
            int rl = wave * 16 + q * 4 + r;
#pragma unroll
            for (int ct = 0; ct < 8; ++ct)
                bounce[rl * BSTR + ct * 16 + m16] = hbv[r][ct];
        }
        __syncthreads();
        int rl = t >> 2;
        int grow = blockIdx.x * 64 + rl;
        if (grow < N_NODES) {
            const unsigned short* bp = bounce + rl * BSTR + (t & 3) * 32;
            unsigned o[8];
#pragma unroll
            for (int k = 0; k < 4; ++k) {
                bf16x8 bv = *(const bf16x8*)(bp + k * 8);
                pack8_fp8(bv, o[2 * k], o[2 * k + 1]);
            }
            u32x4* dp = (u32x4*)(hb8 + (size_t)grow * 128 + (t & 3) * 32);
            dp[0] = (u32x4){o[0], o[1], o[2], o[3]};
            dp[1] = (u32x4){o[4], o[5], o[6], o[7]};
        }
    }
}

// ---------------- launch ----------------

extern "C" void kernel_launch(void* const* d_in, const int* in_sizes, int n_in,
                              void* d_out, int out_size, void* d_ws, size_t ws_size,
                              hipStream_t stream) {
    const float* x          = (const float*)d_in[0];
    const int*   label      = (const int*)d_in[1];
    const int*   edge_index = (const int*)d_in[2];
    const int*   edge_rel   = (const int*)d_in[3];
    const float* label_emb  = (const float*)d_in[4];
    const float* in_proj_w  = (const float*)d_in[5];
    const float* in_proj_b  = (const float*)d_in[6];
    const float* rel_emb    = (const float*)d_in[7];
    const float* lin_neigh_w = (const float*)d_in[8];
    const float* lin_self_w  = (const float*)d_in[9];
    const float* lin_self_b  = (const float*)d_in[10];
    const float* lin_rel_w   = (const float*)d_in[11];
    const float* ln_g        = (const float*)d_in[12];
    const float* ln_b        = (const float*)d_in[13];
    float* h = (float*)d_out;

    char* p = (char*)d_ws;
    auto alloc = [&](size_t bytes) {
        char* r = p;
        p += (bytes + 255) & ~(size_t)255;
        return r;
    };
    int* gcur        = (int*)alloc((size_t)NB * 4);
    int* off         = (int*)alloc((size_t)N_NODES * 4);
    int* deg         = (int*)alloc((size_t)N_NODES * 4);
    unsigned* csr_pk = (unsigned*)alloc((size_t)NB * CAP * 4);
    unsigned* staged_pk = (unsigned*)alloc((size_t)NB * CAP * 4);
    unsigned char* staged_dl = (unsigned char*)alloc((size_t)NB * CAP);
    unsigned short* hb  = (unsigned short*)alloc((size_t)N_NODES * 128 * 2);
    unsigned char*  hb8 = (unsigned char*)alloc((size_t)N_NODES * 128);
    unsigned short* Sm  = (unsigned short*)alloc((size_t)N_NODES * 128 * 2);
    unsigned short* Rm  = (unsigned short*)alloc((size_t)N_NODES * 32 * 2);
    unsigned short* Btx = (unsigned short*)alloc((size_t)128 * 160 * 2);
    unsigned short* leb = (unsigned short*)alloc((size_t)NUM_LABELS * LABEL_DIM * 2);
    unsigned short* Btc0 = (unsigned short*)alloc((size_t)128 * 288 * 2);
    unsigned short* Btc1 = (unsigned short*)alloc((size_t)128 * 288 * 2);
    unsigned short* relb0 = (unsigned short*)alloc((size_t)REL_BUCKETS * REL_DIM * 2);
    unsigned short* relb1 = (unsigned short*)alloc((size_t)REL_BUCKETS * REL_DIM * 2);

    const int* src = edge_index;
    const int* dst = edge_index + N_EDGES;

    // 0) zero bucket counters (tiny DMA fill)
    hipMemsetAsync(gcur, 0, (size_t)NB * 4, stream);

    // 1) edge scatter || weight/embedding prep (one dispatch)
    scatter_prep_kernel<<<NE_BLOCKS + PREP_UNITS, 256, 0, stream>>>(
        src, dst, edge_rel, gcur, staged_pk, staged_dl,
        in_proj_w, label_emb, lin_neigh_w, lin_self_w, lin_rel_w, rel_emb,
        Btx, leb, Btc0, Btc1, relb0, relb1);

    // 2) per-bucket place || input-proj GEMM (writes hb + fp8 hb8)
    place_in_kernel<<<NB + NE_BLOCKS, 256, 0, stream>>>(
        gcur, staged_pk, staged_dl, off, deg, csr_pk,
        x, Btx, leb, label, in_proj_b, hb, hb8);

    const int gemm_grid = (N_NODES + 63) / 64;  // 782
    const int agg_grid = (N_NODES + 3) / 4;     // 12500

    // 3-4) layer 0
    agg_raw_kernel<<<agg_grid, 256, 0, stream>>>(
        hb8, relb0, off, deg, csr_pk, Sm, Rm);
    gemm_ln_kernel<false><<<gemm_grid, 256, 0, stream>>>(
        Btc0, hb, hb8, Sm, Rm, lin_self_b, ln_g, ln_b, nullptr);
    // 5-6) layer 1
    agg_raw_kernel<<<agg_grid, 256, 0, stream>>>(
        hb8, relb1, off, deg, csr_pk, Sm, Rm);
    gemm_ln_kernel<true><<<gemm_grid, 256, 0, stream>>>(
        Btc1, hb, hb8, Sm, Rm, lin_self_b + 128, ln_g + 128, ln_b + 128, h);
}

// Round 10
// 223.890 us; speedup vs baseline: 1.2727x; 1.0101x over previous
//
#include <hip/hip_runtime.h>
#include <hip/hip_bf16.h>

#define N_NODES 50000
#define N_EDGES 800000
#define D 128
#define LABEL_DIM 32
#define REL_DIM 32
#define REL_BUCKETS 1024
#define NUM_LABELS 1000
#define LN_EPS 1e-5f

#define NB 196       // dst buckets of 256 nodes
#define CAP 6144     // fixed per-bucket capacity (mean load 4082, +32 sigma headroom)
#define EPB 2048     // edges per scatter block (8/thread)
#define NE_BLOCKS 391
#define GB 782       // input-GEMM blocks

#define PB_IN 80      // 128*160/256
#define PB_LEMB 125   // 32000/256
#define PB_CAT 144    // 128*288/256 per layer
#define PB_REL 32     // 32768/1024 per layer
#define PREP_UNITS (PB_IN + PB_LEMB + 2 * PB_CAT + 2 * PB_REL)   // 557

#define BSTR 144     // bounce LDS row stride in shorts (288B, 16B-aligned rows)

typedef short bf16x8 __attribute__((ext_vector_type(8)));
typedef float f32x4 __attribute__((ext_vector_type(4)));
typedef float f32x2 __attribute__((ext_vector_type(2)));
typedef unsigned int u32x2 __attribute__((ext_vector_type(2)));
typedef unsigned int u32x4 __attribute__((ext_vector_type(4)));

__device__ inline unsigned short f2bf(float f) {
    __hip_bfloat16 h = __float2bfloat16(f);
    return *reinterpret_cast<unsigned short*>(&h);
}
__device__ inline float bf2f(unsigned short u) {
    return __uint_as_float((unsigned)u << 16);
}

// pack 8 bf16 (as shorts) -> 8 fp8 e4m3 bytes (2 dwords) via HW cvt
__device__ inline void pack8_fp8(const bf16x8 bv, unsigned& lo, unsigned& hi) {
    float f0 = bf2f((unsigned short)bv[0]), f1 = bf2f((unsigned short)bv[1]);
    float f2 = bf2f((unsigned short)bv[2]), f3 = bf2f((unsigned short)bv[3]);
    float f4 = bf2f((unsigned short)bv[4]), f5 = bf2f((unsigned short)bv[5]);
    float f6 = bf2f((unsigned short)bv[6]), f7 = bf2f((unsigned short)bv[7]);
    lo = __builtin_amdgcn_cvt_pk_fp8_f32(f0, f1, 0u, false);
    lo = __builtin_amdgcn_cvt_pk_fp8_f32(f2, f3, lo, true);
    hi = __builtin_amdgcn_cvt_pk_fp8_f32(f4, f5, 0u, false);
    hi = __builtin_amdgcn_cvt_pk_fp8_f32(f6, f7, hi, true);
}

// ---------------- fused: edge scatter (blocks 0..390) || weight prep (391..) ----------------
__global__ __launch_bounds__(256) void scatter_prep_kernel(
    const int* __restrict__ src, const int* __restrict__ dst, const int* __restrict__ rel,
    int* __restrict__ gcur, unsigned* __restrict__ staged_pk, unsigned char* __restrict__ staged_dl,
    const float* __restrict__ in_proj_w, const float* __restrict__ label_emb,
    const float* __restrict__ lin_neigh_w, const float* __restrict__ lin_self_w,
    const float* __restrict__ lin_rel_w, const float* __restrict__ rel_emb,
    unsigned short* __restrict__ Btx, unsigned short* __restrict__ leb,
    unsigned short* __restrict__ Btc0, unsigned short* __restrict__ Btc1,
    unsigned short* __restrict__ relb0, unsigned short* __restrict__ relb1) {
    __shared__ int hist[NB];
    __shared__ int lcur[NB];
    const int t = threadIdx.x;
    const int bid = blockIdx.x;

    if (bid >= NE_BLOCKS) {
        int u = bid - NE_BLOCKS;
        if (u < PB_IN) {
            int idx = u * 256 + t;
            int n = idx / 160, k = idx % 160;
            Btx[idx] = f2bf(in_proj_w[k * 128 + n]);
            return;
        }
        u -= PB_IN;
        if (u < PB_LEMB) {
            int i = u * 256 + t;
            if (i < NUM_LABELS * LABEL_DIM) leb[i] = f2bf(label_emb[i]);
            return;
        }
        u -= PB_LEMB;
        if (u < 2 * PB_CAT) {
            int l = u >= PB_CAT;
            int cb = l ? u - PB_CAT : u;
            int idx = cb * 256 + t;           // 0..36863
            int n = idx / 288, k = idx % 288; // Btc[n*288 + k] = Wcat[k][n]
            const float* Ws = lin_self_w + (size_t)l * 128 * 128;
            const float* Wn = lin_neigh_w + (size_t)l * 128 * 128;
            const float* Wr = lin_rel_w + (size_t)l * REL_DIM * 128;
            float v = (k < 128) ? Ws[(size_t)k * 128 + n]
                    : (k < 256) ? Wn[(size_t)(k - 128) * 128 + n]
                                : Wr[(size_t)(k - 256) * 128 + n];
            (l ? Btc1 : Btc0)[idx] = f2bf(v);
            return;
        }
        u -= 2 * PB_CAT;
        {   // rel_emb fp32 -> bf16 tables (halves rel gather bytes)
            int l = u >= PB_REL;
            int rb = l ? u - PB_REL : u;
            int idx = rb * 1024 + t * 4;
            float4 v = *(const float4*)(rel_emb + (size_t)l * REL_BUCKETS * REL_DIM + idx);
            unsigned short* out = (l ? relb1 : relb0) + idx;
            out[0] = f2bf(v.x); out[1] = f2bf(v.y);
            out[2] = f2bf(v.z); out[3] = f2bf(v.w);
            return;
        }
    }

    // ---- edge scatter into fixed-capacity bucket regions (8 edges/thread) ----
    for (int i = t; i < NB; i += 256) hist[i] = 0;
    __syncthreads();
    const int e0 = bid * EPB;
    unsigned char bb[8], dl[8];
#pragma unroll
    for (int i = 0; i < 8; ++i) {
        int e = e0 + i * 256 + t;
        if (e < N_EDGES) {
            int d = dst[e];
            bb[i] = (unsigned char)(d >> 8);
            dl[i] = (unsigned char)(d & 255);
            atomicAdd(&hist[d >> 8], 1);
        }
    }
    __syncthreads();
    for (int b = t; b < NB; b += 256) {
        int hc = hist[b];
        lcur[b] = hc ? (b * CAP + atomicAdd(&gcur[b], hc)) : 0;
    }
    __syncthreads();
#pragma unroll
    for (int i = 0; i < 8; ++i) {
        int e = e0 + i * 256 + t;
        if (e < N_EDGES) {
            int pos = atomicAdd(&lcur[bb[i]], 1);
            staged_pk[pos] = (unsigned)src[e] | ((unsigned)rel[e] << 16);
            staged_dl[pos] = dl[i];
        }
    }
}

// ---------------- fused dispatch: per-bucket place (0..195) || input GEMM (196..977) ----------------
__global__ __launch_bounds__(256) void place_in_kernel(
    const int* __restrict__ gcur,
    const unsigned* __restrict__ staged_pk, const unsigned char* __restrict__ staged_dl,
    int* __restrict__ off, int* __restrict__ deg, unsigned* __restrict__ csr_pk,
    const float* __restrict__ X, const unsigned short* __restrict__ Btx,
    const unsigned short* __restrict__ leb, const int* __restrict__ label,
    const float* __restrict__ bias, unsigned short* __restrict__ hb,
    unsigned char* __restrict__ hb8) {
    __shared__ __align__(16) char smem[128 * 160 * 2];   // 40 KiB union
    const int t = threadIdx.x;
    const int bid = blockIdx.x;

    if (bid < NB) {
        int* ph = (int*)smem;
        int* pbuf = ph + 256;
        int* pcur = pbuf + 256;
        const int beg = bid * CAP;
        const int end = beg + gcur[bid];
        ph[t] = 0;
        __syncthreads();
        for (int i = beg + t; i < end; i += 256) atomicAdd(&ph[staged_dl[i]], 1);
        __syncthreads();
        int v = ph[t];
        pbuf[t] = v;
        __syncthreads();
        for (int o = 1; o < 256; o <<= 1) {
            int tv = (t >= o) ? pbuf[t - o] : 0;
            __syncthreads();
            pbuf[t] += tv;
            __syncthreads();
        }
        int node_off = beg + pbuf[t] - v;
        int node = bid * 256 + t;
        if (node < N_NODES) {
            off[node] = node_off;
            deg[node] = v;
        }
        pcur[t] = node_off;
        __syncthreads();
        for (int i = beg + t; i < end; i += 256) {
            int pos = atomicAdd(&pcur[staged_dl[i]], 1);
            csr_pk[pos] = staged_pk[i];
        }
        return;
    }

    // ---- input-proj MFMA GEMM (fp32 A, K=160, fused label-emb + bias + relu) ----
    unsigned short* sB = (unsigned short*)smem;
    const int mb = bid - NB;   // 0..781
#pragma unroll
    for (int i = 0; i < 10; ++i) {
        int c = t + i * 256;
        int col = c / 20, kch = c % 20;
        int dstc = col * 20 + (kch < 16 ? (kch ^ (col & 7)) : kch);
        *(bf16x8*)&sB[dstc * 8] = *(const bf16x8*)&Btx[c * 8];
    }
    __syncthreads();

    const int wave = t >> 6, lane = t & 63;
    const int m16 = lane & 15, q = lane >> 4;
    const int r0 = mb * 64 + wave * 16;
    const int arow = r0 + m16;
    const bool avalid = arow < N_NODES;
    const float* xp = X + (size_t)(avalid ? arow : 0) * 128 + q * 8;

    f32x4 acc[8];
#pragma unroll
    for (int ct = 0; ct < 8; ++ct) acc[ct] = (f32x4){0.f, 0.f, 0.f, 0.f};

#pragma unroll
    for (int ki = 0; ki < 4; ++ki) {
        bf16x8 af;
        if (avalid) {
            float4 v0 = *(const float4*)(xp + ki * 32);
            float4 v1 = *(const float4*)(xp + ki * 32 + 4);
            af[0] = (short)f2bf(v0.x); af[1] = (short)f2bf(v0.y);
            af[2] = (short)f2bf(v0.z); af[3] = (short)f2bf(v0.w);
            af[4] = (short)f2bf(v1.x); af[5] = (short)f2bf(v1.y);
            af[6] = (short)f2bf(v1.z); af[7] = (short)f2bf(v1.w);
        } else {
            af = (bf16x8){0, 0, 0, 0, 0, 0, 0, 0};
        }
        int kch = ki * 4 + q;
#pragma unroll
        for (int ct = 0; ct < 8; ++ct) {
            int col = ct * 16 + m16;
            int chunk = col * 20 + (kch ^ (m16 & 7));
            bf16x8 bf = *(const bf16x8*)&sB[chunk * 8];
            acc[ct] = __builtin_amdgcn_mfma_f32_16x16x32_bf16(af, bf, acc[ct], 0, 0, 0);
        }
    }
    {
        int lb = avalid ? label[arow] : 0;
        bf16x8 af = *(const bf16x8*)(leb + (size_t)lb * LABEL_DIM + q * 8);
        if (!avalid) af = (bf16x8){0, 0, 0, 0, 0, 0, 0, 0};
        int kch = 16 + q;
#pragma unroll
        for (int ct = 0; ct < 8; ++ct) {
            int col = ct * 16 + m16;
            int chunk = col * 20 + kch;
            bf16x8 bf = *(const bf16x8*)&sB[chunk * 8];
            acc[ct] = __builtin_amdgcn_mfma_f32_16x16x32_bf16(af, bf, acc[ct], 0, 0, 0);
        }
    }

    unsigned short hbv[8][4];
#pragma unroll
    for (int ct = 0; ct < 8; ++ct) {
        int colg = ct * 16 + m16;
        float bs = bias[colg];
#pragma unroll
        for (int r = 0; r < 4; ++r) {
            int row = r0 + q * 4 + r;
            float v = fmaxf(acc[ct][r] + bs, 0.f);
            hbv[ct][r] = f2bf(v);
            if (row < N_NODES) hb[(size_t)row * 128 + colg] = hbv[ct][r];
        }
    }

    // fp8 shadow copy via LDS bounce (accumulator cols are 16-strided; need contiguity)
    __syncthreads();
    unsigned short* bounce = sB;
#pragma unroll
    for (int ct = 0; ct < 8; ++ct) {
        int colg = ct * 16 + m16;
#pragma unroll
        for (int r = 0; r < 4; ++r)
            bounce[(wave * 16 + q * 4 + r) * BSTR + colg] = hbv[ct][r];
    }
    __syncthreads();
    {
        int rl = t >> 2;
        int grow = mb * 64 + rl;
        if (grow < N_NODES) {
            const unsigned short* bp = bounce + rl * BSTR + (t & 3) * 32;
            unsigned o[8];
#pragma unroll
            for (int k = 0; k < 4; ++k) {
                bf16x8 bv = *(const bf16x8*)(bp + k * 8);
                pack8_fp8(bv, o[2 * k], o[2 * k + 1]);
            }
            u32x4* dp = (u32x4*)(hb8 + (size_t)grow * 128 + (t & 3) * 32);
            dp[0] = (u32x4){o[0], o[1], o[2], o[3]};
            dp[1] = (u32x4){o[4], o[5], o[6], o[7]};
        }
    }
}

// ---------------- raw-neighbor aggregation (fp8 h rows + bf16 rel rows) ----------------
// Latency-optimized: coalesced csr_pk prefetch (1 load covers deg<=64) + __shfl
// distribution + 16 edges in flight per iteration (8 independent gathers/lane).
__global__ __launch_bounds__(256) void agg_raw_kernel(const unsigned char* __restrict__ hb8,
                                                      const unsigned short* __restrict__ relb,
                                                      const int* __restrict__ off,
                                                      const int* __restrict__ deg,
                                                      const unsigned* __restrict__ csr_pk,
                                                      unsigned short* __restrict__ Sm,
                                                      unsigned short* __restrict__ Rm) {
    const int wave = threadIdx.x >> 6;
    const int lane = threadIdx.x & 63;
    const int node = blockIdx.x * 4 + wave;
    if (node >= N_NODES) return;
    const int q = lane >> 4, l16 = lane & 15;
    const int beg = off[node];
    const int dcnt = deg[node];
    const int co = l16 * 8;

    float acc[8];
    float ra0 = 0.f, ra1 = 0.f;
#pragma unroll
    for (int j = 0; j < 8; ++j) acc[j] = 0.f;

    // coalesced prefetch of up to 64 packed edge records (covers ~100% of nodes)
    unsigned pkv = 0;
    if (lane < dcnt) pkv = csr_pk[beg + lane];

    const int dcl = dcnt < 64 ? dcnt : 64;
    for (int s = 0; s < dcl; s += 16) {
        unsigned pkk[4];
        float mk[4];
#pragma unroll
        for (int k = 0; k < 4; ++k) {
            int slot = s + k * 4 + q;          // <= 63 always
            pkk[k] = (unsigned)__shfl((int)pkv, slot);
            mk[k] = (slot < dcnt) ? 1.f : 0.f; // masked lanes read row 0 (safe)
        }
#pragma unroll
        for (int k = 0; k < 4; ++k) {
            u32x2 hv = *(const u32x2*)(hb8 + ((size_t)(pkk[k] & 0xffffu) << 7) + co);
            unsigned rw = *(const unsigned*)(relb + ((size_t)(pkk[k] >> 16) << 5) + l16 * 2);
            float m = mk[k];
            f32x2 d0 = __builtin_amdgcn_cvt_pk_f32_fp8(hv[0], false);
            f32x2 d1 = __builtin_amdgcn_cvt_pk_f32_fp8(hv[0], true);
            f32x2 d2 = __builtin_amdgcn_cvt_pk_f32_fp8(hv[1], false);
            f32x2 d3 = __builtin_amdgcn_cvt_pk_f32_fp8(hv[1], true);
            acc[0] = fmaf(m, d0[0], acc[0]); acc[1] = fmaf(m, d0[1], acc[1]);
            acc[2] = fmaf(m, d1[0], acc[2]); acc[3] = fmaf(m, d1[1], acc[3]);
            acc[4] = fmaf(m, d2[0], acc[4]); acc[5] = fmaf(m, d2[1], acc[5]);
            acc[6] = fmaf(m, d3[0], acc[6]); acc[7] = fmaf(m, d3[1], acc[7]);
            ra0 = fmaf(m, bf2f((unsigned short)(rw & 0xffffu)), ra0);
            ra1 = fmaf(m, bf2f((unsigned short)(rw >> 16)), ra1);
        }
    }

    // rare tail: deg > 64
    const int end = beg + dcnt;
    for (int e = beg + 64; e < end; e += 8) {
        int i0 = e + q, i1 = e + 4 + q;
        float m0 = 1.f, m1 = 1.f;
        if (i0 >= end) { i0 = beg; m0 = 0.f; }
        if (i1 >= end) { i1 = beg; m1 = 0.f; }
        unsigned pk0 = csr_pk[i0];
        unsigned pk1 = csr_pk[i1];
        u32x2 hv0 = *(const u32x2*)(hb8 + ((size_t)(pk0 & 0xffffu) << 7) + co);
        u32x2 hv1 = *(const u32x2*)(hb8 + ((size_t)(pk1 & 0xffffu) << 7) + co);
        unsigned rw0 = *(const unsigned*)(relb + ((size_t)(pk0 >> 16) << 5) + l16 * 2);
        unsigned rw1 = *(const unsigned*)(relb + ((size_t)(pk1 >> 16) << 5) + l16 * 2);
        {
            f32x2 d0 = __builtin_amdgcn_cvt_pk_f32_fp8(hv0[0], false);
            f32x2 d1 = __builtin_amdgcn_cvt_pk_f32_fp8(hv0[0], true);
            f32x2 d2 = __builtin_amdgcn_cvt_pk_f32_fp8(hv0[1], false);
            f32x2 d3 = __builtin_amdgcn_cvt_pk_f32_fp8(hv0[1], true);
            acc[0] = fmaf(m0, d0[0], acc[0]); acc[1] = fmaf(m0, d0[1], acc[1]);
            acc[2] = fmaf(m0, d1[0], acc[2]); acc[3] = fmaf(m0, d1[1], acc[3]);
            acc[4] = fmaf(m0, d2[0], acc[4]); acc[5] = fmaf(m0, d2[1], acc[5]);
            acc[6] = fmaf(m0, d3[0], acc[6]); acc[7] = fmaf(m0, d3[1], acc[7]);
        }
        {
            f32x2 d0 = __builtin_amdgcn_cvt_pk_f32_fp8(hv1[0], false);
            f32x2 d1 = __builtin_amdgcn_cvt_pk_f32_fp8(hv1[0], true);
            f32x2 d2 = __builtin_amdgcn_cvt_pk_f32_fp8(hv1[1], false);
            f32x2 d3 = __builtin_amdgcn_cvt_pk_f32_fp8(hv1[1], true);
            acc[0] = fmaf(m1, d0[0], acc[0]); acc[1] = fmaf(m1, d0[1], acc[1]);
            acc[2] = fmaf(m1, d1[0], acc[2]); acc[3] = fmaf(m1, d1[1], acc[3]);
            acc[4] = fmaf(m1, d2[0], acc[4]); acc[5] = fmaf(m1, d2[1], acc[5]);
            acc[6] = fmaf(m1, d3[0], acc[6]); acc[7] = fmaf(m1, d3[1], acc[7]);
        }
        ra0 = fmaf(m0, bf2f((unsigned short)(rw0 & 0xffffu)), ra0);
        ra1 = fmaf(m0, bf2f((unsigned short)(rw0 >> 16)), ra1);
        ra0 = fmaf(m1, bf2f((unsigned short)(rw1 & 0xffffu)), ra0);
        ra1 = fmaf(m1, bf2f((unsigned short)(rw1 >> 16)), ra1);
    }

#pragma unroll
    for (int j = 0; j < 8; ++j) {
        acc[j] += __shfl_xor(acc[j], 16);
        acc[j] += __shfl_xor(acc[j], 32);
    }
    ra0 += __shfl_xor(ra0, 16); ra0 += __shfl_xor(ra0, 32);
    ra1 += __shfl_xor(ra1, 16); ra1 += __shfl_xor(ra1, 32);

    float inv = (dcnt > 0) ? 1.f / (float)dcnt : 0.f;
    if (q == 0) {
        bf16x8 ob;
#pragma unroll
        for (int j = 0; j < 8; ++j) ob[j] = (short)f2bf(acc[j] * inv);
        *(bf16x8*)(Sm + ((size_t)node << 7) + co) = ob;
        unsigned pk = (unsigned)f2bf(ra0 * inv) | ((unsigned)f2bf(ra1 * inv) << 16);
        ((unsigned*)(Rm + ((size_t)node << 5)))[l16] = pk;
    }
}

// ---------------- fused K=288 GEMM [h|Sm|Rm]@[Wself;Wneigh;Wrel] + bias+relu+LN ----
// Split-B staging (B1 self 32KB -> MFMA -> B2 neigh+rel 40KB) keeps LDS at 40KB
// -> 4 blocks/CU. Sm/Rm A-fragments + epilogue scalars are prefetched into regs
// BEFORE the B2 staging so global latency hides under the LDS writes/barrier.
template <bool LAST>
__global__ __launch_bounds__(256, 4) void gemm_ln_kernel(const unsigned short* __restrict__ Btc,
                                                         unsigned short* __restrict__ hb,
                                                         unsigned char* __restrict__ hb8,
                                                         const unsigned short* __restrict__ Sm,
                                                         const unsigned short* __restrict__ Rm,
                                                         const float* __restrict__ bias,
                                                         const float* __restrict__ g,
                                                         const float* __restrict__ b,
                                                         float* __restrict__ hout) {
    __shared__ unsigned short sB[128 * 20 * 8];  // 40 KiB, staged twice
    const int t = threadIdx.x;
    const int wave = t >> 6, lane = t & 63;
    const int m16 = lane & 15, q = lane >> 4;
    const int r0 = blockIdx.x * 64 + wave * 16;
    const int arow = r0 + m16;
    const bool avalid = arow < N_NODES;
    const int sr = avalid ? arow : 0;
    const unsigned short* hp = hb + (size_t)sr * 128 + q * 8;
    const unsigned short* sp = Sm + (size_t)sr * 128 + q * 8;
    const unsigned short* rp = Rm + (size_t)sr * 32 + q * 8;
    const bf16x8 zf = (bf16x8){0, 0, 0, 0, 0, 0, 0, 0};

    // preload self A fragments (independent of LDS)
    bf16x8 aself[4];
#pragma unroll
    for (int ki = 0; ki < 4; ++ki) {
        bf16x8 af = *(const bf16x8*)(hp + ki * 32);
        aself[ki] = avalid ? af : zf;
    }

    // stage B1: self K-chunks 0..15 (32 KiB)
#pragma unroll
    for (int i = 0; i < 8; ++i) {
        int c = t + i * 256;              // < 2048
        int col = c >> 4, kc = c & 15;
        *(bf16x8*)&sB[(col * 16 + (kc ^ (col & 7))) * 8] = *(const bf16x8*)&Btc[(col * 36 + kc) * 8];
    }
    __syncthreads();

    f32x4 acc[8];
#pragma unroll
    for (int ct = 0; ct < 8; ++ct) acc[ct] = (f32x4){0.f, 0.f, 0.f, 0.f};

#pragma unroll
    for (int ki = 0; ki < 4; ++ki) {  // k 0..127: self
        int kch = ki * 4 + q;
#pragma unroll
        for (int ct = 0; ct < 8; ++ct) {
            int col = ct * 16 + m16;
            bf16x8 bf = *(const bf16x8*)&sB[(col * 16 + (kch ^ (m16 & 7))) * 8];
            acc[ct] = __builtin_amdgcn_mfma_f32_16x16x32_bf16(aself[ki], bf, acc[ct], 0, 0, 0);
        }
    }

    // prefetch neigh/rel A-fragments + epilogue scalars BEFORE B2 staging:
    // their global latency hides under the LDS writes + barrier below.
    bf16x8 aneigh[4];
#pragma unroll
    for (int ki = 0; ki < 4; ++ki) {
        bf16x8 af = *(const bf16x8*)(sp + ki * 32);
        aneigh[ki] = avalid ? af : zf;
    }
    bf16x8 arel = avalid ? *(const bf16x8*)rp : zf;
    float bs[8], gs[8], bbs[8];
#pragma unroll
    for (int ct = 0; ct < 8; ++ct) {
        int cg2 = ct * 16 + m16;
        bs[ct] = bias[cg2];
        gs[ct] = g[cg2];
        bbs[ct] = b[cg2];
    }
    __syncthreads();

    // stage B2: neigh K-chunks 16..31 + rel 32..35 remapped to local 0..19 (40 KiB)
#pragma unroll
    for (int i = 0; i < 10; ++i) {
        int c = t + i * 256;              // < 2560
        int col = c / 20, j = c % 20;
        int swz = (j < 16) ? (j ^ (col & 7)) : (16 + ((j - 16) ^ (col & 3)));
        *(bf16x8*)&sB[(col * 20 + swz) * 8] = *(const bf16x8*)&Btc[(col * 36 + 16 + j) * 8];
    }
    __syncthreads();

#pragma unroll
    for (int ki = 0; ki < 4; ++ki) {  // k 128..255: neigh-mean
        int kch = ki * 4 + q;         // local chunk in B2
#pragma unroll
        for (int ct = 0; ct < 8; ++ct) {
            int col = ct * 16 + m16;
            bf16x8 bf = *(const bf16x8*)&sB[(col * 20 + (kch ^ (m16 & 7))) * 8];
            acc[ct] = __builtin_amdgcn_mfma_f32_16x16x32_bf16(aneigh[ki], bf, acc[ct], 0, 0, 0);
        }
    }
    {  // k 256..287: rel-mean (local chunks 16..19)
#pragma unroll
        for (int ct = 0; ct < 8; ++ct) {
            int col = ct * 16 + m16;
            bf16x8 bf = *(const bf16x8*)&sB[(col * 20 + 16 + (q ^ (m16 & 3))) * 8];
            acc[ct] = __builtin_amdgcn_mfma_f32_16x16x32_bf16(arel, bf, acc[ct], 0, 0, 0);
        }
    }

    // epilogue: bias + relu + layernorm per row (16 lanes of same q hold one row)
    unsigned short hbv[4][8];
#pragma unroll
    for (int r = 0; r < 4; ++r) {
        int row = r0 + q * 4 + r;
        float v[8];
        float s = 0.f;
#pragma unroll
        for (int ct = 0; ct < 8; ++ct) {
            float val = fmaxf(acc[ct][r] + bs[ct], 0.f);
            v[ct] = val;
            s += val;
        }
#pragma unroll
        for (int o = 8; o > 0; o >>= 1) s += __shfl_xor(s, o);
        float mu = s * (1.f / 128.f);
        float qs = 0.f;
#pragma unroll
        for (int ct = 0; ct < 8; ++ct) {
            float dd = v[ct] - mu;
            v[ct] = dd;
            qs += dd * dd;
        }
#pragma unroll
        for (int o = 8; o > 0; o >>= 1) qs += __shfl_xor(qs, o);
        float rstd = rsqrtf(qs * (1.f / 128.f) + LN_EPS);
#pragma unroll
        for (int ct = 0; ct < 8; ++ct) {
            int colg = ct * 16 + m16;
            float o2 = v[ct] * rstd * gs[ct] + bbs[ct];
            hbv[r][ct] = f2bf(o2);
            if (row < N_NODES) {
                if constexpr (LAST) {
                    hout[(size_t)row * 128 + colg] = o2;
                } else {
                    hb[(size_t)row * 128 + colg] = hbv[r][ct];
                }
            }
        }
    }

    if constexpr (!LAST) {
        // fp8 shadow copy via LDS bounce (reuse sB: 64*BSTR = 18KB < 40KB)
        __syncthreads();
        unsigned short* bounce = sB;
#pragma unroll
        for (int r = 0; r < 4; ++r) {
            int rl = wave * 16 + q * 4 + r;
#pragma unroll
            for (int ct = 0; ct < 8; ++ct)
                bounce[rl * BSTR + ct * 16 + m16] = hbv[r][ct];
        }
        __syncthreads();
        int rl = t >> 2;
        int grow = blockIdx.x * 64 + rl;
        if (grow < N_NODES) {
            const unsigned short* bp = bounce + rl * BSTR + (t & 3) * 32;
            unsigned o[8];
#pragma unroll
            for (int k = 0; k < 4; ++k) {
                bf16x8 bv = *(const bf16x8*)(bp + k * 8);
                pack8_fp8(bv, o[2 * k], o[2 * k + 1]);
            }
            u32x4* dp = (u32x4*)(hb8 + (size_t)grow * 128 + (t & 3) * 32);
            dp[0] = (u32x4){o[0], o[1], o[2], o[3]};
            dp[1] = (u32x4){o[4], o[5], o[6], o[7]};
        }
    }
}

// ---------------- launch ----------------

extern "C" void kernel_launch(void* const* d_in, const int* in_sizes, int n_in,
                              void* d_out, int out_size, void* d_ws, size_t ws_size,
                              hipStream_t stream) {
    const float* x          = (const float*)d_in[0];
    const int*   label      = (const int*)d_in[1];
    const int*   edge_index = (const int*)d_in[2];
    const int*   edge_rel   = (const int*)d_in[3];
    const float* label_emb  = (const float*)d_in[4];
    const float* in_proj_w  = (const float*)d_in[5];
    const float* in_proj_b  = (const float*)d_in[6];
    const float* rel_emb    = (const float*)d_in[7];
    const float* lin_neigh_w = (const float*)d_in[8];
    const float* lin_self_w  = (const float*)d_in[9];
    const float* lin_self_b  = (const float*)d_in[10];
    const float* lin_rel_w   = (const float*)d_in[11];
    const float* ln_g        = (const float*)d_in[12];
    const float* ln_b        = (const float*)d_in[13];
    float* h = (float*)d_out;

    char* p = (char*)d_ws;
    auto alloc = [&](size_t bytes) {
        char* r = p;
        p += (bytes + 255) & ~(size_t)255;
        return r;
    };
    int* gcur        = (int*)alloc((size_t)NB * 4);
    int* off         = (int*)alloc((size_t)N_NODES * 4);
    int* deg         = (int*)alloc((size_t)N_NODES * 4);
    unsigned* csr_pk = (unsigned*)alloc((size_t)NB * CAP * 4);
    unsigned* staged_pk = (unsigned*)alloc((size_t)NB * CAP * 4);
    unsigned char* staged_dl = (unsigned char*)alloc((size_t)NB * CAP);
    unsigned short* hb  = (unsigned short*)alloc((size_t)N_NODES * 128 * 2);
    unsigned char*  hb8 = (unsigned char*)alloc((size_t)N_NODES * 128);
    unsigned short* Sm  = (unsigned short*)alloc((size_t)N_NODES * 128 * 2);
    unsigned short* Rm  = (unsigned short*)alloc((size_t)N_NODES * 32 * 2);
    unsigned short* Btx = (unsigned short*)alloc((size_t)128 * 160 * 2);
    unsigned short* leb = (unsigned short*)alloc((size_t)NUM_LABELS * LABEL_DIM * 2);
    unsigned short* Btc0 = (unsigned short*)alloc((size_t)128 * 288 * 2);
    unsigned short* Btc1 = (unsigned short*)alloc((size_t)128 * 288 * 2);
    unsigned short* relb0 = (unsigned short*)alloc((size_t)REL_BUCKETS * REL_DIM * 2);
    unsigned short* relb1 = (unsigned short*)alloc((size_t)REL_BUCKETS * REL_DIM * 2);

    const int* src = edge_index;
    const int* dst = edge_index + N_EDGES;

    // 0) zero bucket counters (tiny DMA fill)
    hipMemsetAsync(gcur, 0, (size_t)NB * 4, stream);

    // 1) edge scatter || weight/embedding prep (one dispatch)
    scatter_prep_kernel<<<NE_BLOCKS + PREP_UNITS, 256, 0, stream>>>(
        src, dst, edge_rel, gcur, staged_pk, staged_dl,
        in_proj_w, label_emb, lin_neigh_w, lin_self_w, lin_rel_w, rel_emb,
        Btx, leb, Btc0, Btc1, relb0, relb1);

    // 2) per-bucket place || input-proj GEMM (writes hb + fp8 hb8)
    place_in_kernel<<<NB + GB, 256, 0, stream>>>(
        gcur, staged_pk, staged_dl, off, deg, csr_pk,
        x, Btx, leb, label, in_proj_b, hb, hb8);

    const int gemm_grid = GB;                   // 782
    const int agg_grid = (N_NODES + 3) / 4;     // 12500

    // 3-4) layer 0
    agg_raw_kernel<<<agg_grid, 256, 0, stream>>>(
        hb8, relb0, off, deg, csr_pk, Sm, Rm);
    gemm_ln_kernel<false><<<gemm_grid, 256, 0, stream>>>(
        Btc0, hb, hb8, Sm, Rm, lin_self_b, ln_g, ln_b, nullptr);
    // 5-6) layer 1
    agg_raw_kernel<<<agg_grid, 256, 0, stream>>>(
        hb8, relb1, off, deg, csr_pk, Sm, Rm);
    gemm_ln_kernel<true><<<gemm_grid, 256, 0, stream>>>(
        Btc1, hb, hb8, Sm, Rm, lin_self_b + 128, ln_g + 128, ln_b + 128, h);
}